// Round 1
// baseline (5838.560 us; speedup 1.0000x reference)
//
#include <hip/hip_runtime.h>
#include <math.h>

#define BN_EPS 1e-5f

// ---------------- degree / norm prep ----------------

__global__ void fill_kernel(float* __restrict__ p, float val, int n) {
    int i = blockIdx.x * blockDim.x + threadIdx.x;
    if (i < n) p[i] = val;
}

__global__ void deg_kernel(const int* __restrict__ dstv, float* __restrict__ deg, int E) {
    int e = blockIdx.x * blockDim.x + threadIdx.x;
    if (e < E) unsafeAtomicAdd(&deg[dstv[e]], 1.0f);
}

__global__ void dinv_kernel(float* __restrict__ deg, int n) {
    int i = blockIdx.x * blockDim.x + threadIdx.x;
    if (i < n) deg[i] = 1.0f / sqrtf(deg[i]);   // deg >= 1 always (self-loop)
}

__global__ void norm_kernel(const int* __restrict__ srcv, const int* __restrict__ dstv,
                            const float* __restrict__ dinv, float* __restrict__ norm, int E) {
    int e = blockIdx.x * blockDim.x + threadIdx.x;
    if (e < E) norm[e] = dinv[srcv[e]] * dinv[dstv[e]];
}

// batch is sorted; start[g] = first node of graph g, start[G] = N
__global__ void boundary_kernel(const int* __restrict__ batch, int* __restrict__ start,
                                int Nn, int G) {
    int i = blockIdx.x * blockDim.x + threadIdx.x;
    if (i >= Nn) return;
    int b = batch[i];
    if (i == 0) {
        for (int g = 0; g <= b; ++g) start[g] = 0;
    } else {
        int p = batch[i - 1];
        for (int g = p + 1; g <= b; ++g) start[g] = i;
    }
    if (i == Nn - 1) {
        for (int g = b + 1; g <= G; ++g) start[g] = Nn;
    }
}

// ---------------- f32 tiled GEMM: C[M,N] = A[M,K] @ W[K,N] ----------------

template<int BM, int BN, int BK, int TM, int TN, int K, int N>
__global__ __launch_bounds__(256)
void gemm_f32(const float* __restrict__ A, const float* __restrict__ W,
              float* __restrict__ C, int M) {
    constexpr int THREADS = (BM / TM) * (BN / TN);
    static_assert(THREADS == 256, "bad tile config");
    __shared__ float As[BK][BM + 4];
    __shared__ float Ws[BK][BN];
    const int tid  = threadIdx.x;
    const int tcol = tid % (BN / TN);
    const int trow = tid / (BN / TN);
    const int r0   = blockIdx.x * BM;

    float acc[TM][TN] = {};

    constexpr int A_LD4 = BM * BK / 4 / THREADS;
    constexpr int W_LD4 = BK * BN / 4 / THREADS;

    for (int kt = 0; kt < K; kt += BK) {
        #pragma unroll
        for (int t = 0; t < A_LD4; ++t) {
            int idx = t * THREADS + tid;          // [0, BM*BK/4)
            int row = idx / (BK / 4);
            int kq  = idx % (BK / 4);
            int gr  = r0 + row; if (gr >= M) gr = M - 1;
            float4 v = *(const float4*)&A[(size_t)gr * K + kt + kq * 4];
            As[kq * 4 + 0][row] = v.x;
            As[kq * 4 + 1][row] = v.y;
            As[kq * 4 + 2][row] = v.z;
            As[kq * 4 + 3][row] = v.w;
        }
        #pragma unroll
        for (int t = 0; t < W_LD4; ++t) {
            int idx = t * THREADS + tid;          // [0, BK*BN/4)
            int kr = idx / (BN / 4);
            int nc = idx % (BN / 4);
            *(float4*)&Ws[kr][nc * 4] = *(const float4*)&W[(size_t)(kt + kr) * N + nc * 4];
        }
        __syncthreads();
        #pragma unroll
        for (int kk = 0; kk < BK; ++kk) {
            float a[TM], b[TN];
            #pragma unroll
            for (int m = 0; m < TM; m += 4) {
                float4 v = *(const float4*)&As[kk][trow * TM + m];
                a[m] = v.x; a[m+1] = v.y; a[m+2] = v.z; a[m+3] = v.w;
            }
            #pragma unroll
            for (int n = 0; n < TN; n += 4) {
                float4 v = *(const float4*)&Ws[kk][tcol * TN + n];
                b[n] = v.x; b[n+1] = v.y; b[n+2] = v.z; b[n+3] = v.w;
            }
            #pragma unroll
            for (int m = 0; m < TM; ++m)
                #pragma unroll
                for (int n = 0; n < TN; ++n)
                    acc[m][n] = fmaf(a[m], b[n], acc[m][n]);
        }
        __syncthreads();
    }
    #pragma unroll
    for (int m = 0; m < TM; ++m) {
        int gr = r0 + trow * TM + m;
        if (gr < M) {
            float4 v = { acc[m][0], acc[m][1], acc[m][2], acc[m][3] };
            *(float4*)&C[(size_t)gr * N + tcol * TN] = v;
        }
    }
}

// ---------------- edge aggregation (scatter-add with f32 atomics) ----------------

template<int C>
__global__ void agg_kernel(const float* __restrict__ feat, float* __restrict__ out,
                           const int* __restrict__ srcv, const int* __restrict__ dstv,
                           const float* __restrict__ norm, int E) {
    constexpr int Q = C / 4;
    int tid = blockIdx.x * blockDim.x + threadIdx.x;
    int e = tid / Q;
    int q = tid % Q;
    if (e >= E) return;
    int s = srcv[e], d = dstv[e];
    float w = norm[e];
    float4 v = *(const float4*)&feat[(size_t)s * C + q * 4];
    float* o = &out[(size_t)d * C + q * 4];
    unsafeAtomicAdd(o + 0, v.x * w);
    unsafeAtomicAdd(o + 1, v.y * w);
    unsafeAtomicAdd(o + 2, v.z * w);
    unsafeAtomicAdd(o + 3, v.w * w);
}

// ---------------- self-loop + bias + BN + relu, in-place on t ----------------

template<int C>
__global__ void finalize_kernel(float* __restrict__ t, const float* __restrict__ agg,
                                const float* __restrict__ dinv,
                                const float* __restrict__ bias,
                                const float* __restrict__ gam, const float* __restrict__ bet,
                                const float* __restrict__ mu,  const float* __restrict__ var,
                                int Nn) {
    constexpr int Q = C / 4;
    int tid = blockIdx.x * blockDim.x + threadIdx.x;
    int i = tid / Q;
    int q = tid % Q;
    if (i >= Nn) return;
    float di = dinv[i];
    float d2 = di * di;
    float4 tv = *(const float4*)&t[(size_t)i * C + q * 4];
    float4 av = *(const float4*)&agg[(size_t)i * C + q * 4];
    float r[4];
    float tvv[4] = { tv.x, tv.y, tv.z, tv.w };
    float avv[4] = { av.x, av.y, av.z, av.w };
    #pragma unroll
    for (int j = 0; j < 4; ++j) {
        int c = q * 4 + j;
        float sc = gam[c] / sqrtf(var[c] + BN_EPS);
        float sh = bet[c] - mu[c] * sc;
        float h  = avv[j] + tvv[j] * d2 + bias[c];
        float o  = h * sc + sh;
        r[j] = fmaxf(o, 0.0f);
    }
    float4 rv = { r[0], r[1], r[2], r[3] };
    *(float4*)&t[(size_t)i * C + q * 4] = rv;
}

// ---------------- pool + MLP head ----------------

__global__ __launch_bounds__(64)
void pool_mlp_kernel(const float* __restrict__ h3, const int* __restrict__ start,
                     const float* __restrict__ Wm1, const float* __restrict__ bm1,
                     const float* __restrict__ Wm2, const float* __restrict__ bm2,
                     float* __restrict__ out) {
    int g = blockIdx.x;
    int c = threadIdx.x;  // 64
    int s = start[g], e = start[g + 1];
    float sum = 0.0f;
    for (int i = s; i < e; ++i) sum += h3[(size_t)i * 64 + c];
    float cnt = (float)(e - s);
    float pooled = sum / fmaxf(cnt, 1.0f);
    __shared__ float pl[64];
    __shared__ float zl[64];
    pl[c] = pooled;
    __syncthreads();
    float z = bm1[c];
    for (int j = 0; j < 64; ++j) z = fmaf(pl[j], Wm1[j * 64 + c], z);
    z = fmaxf(z, 0.0f);
    zl[c] = z;
    __syncthreads();
    if (c < 10) {
        float o = bm2[c];
        for (int j = 0; j < 64; ++j) o = fmaf(zl[j], Wm2[j * 10 + c], o);
        out[g * 10 + c] = o;
    }
}

// ---------------- launcher ----------------

static inline int cdiv(int a, int b) { return (a + b - 1) / b; }

extern "C" void kernel_launch(void* const* d_in, const int* in_sizes, int n_in,
                              void* d_out, int out_size, void* d_ws, size_t ws_size,
                              hipStream_t stream) {
    const float* x   = (const float*)d_in[0];
    const int* edge  = (const int*)d_in[1];
    const int* batch = (const int*)d_in[2];
    const float* W1  = (const float*)d_in[3];
    const float* b1  = (const float*)d_in[4];
    const float* W2  = (const float*)d_in[5];
    const float* b2  = (const float*)d_in[6];
    const float* W3  = (const float*)d_in[7];
    const float* b3  = (const float*)d_in[8];
    const float* g1  = (const float*)d_in[9];
    const float* be1 = (const float*)d_in[10];
    const float* m1  = (const float*)d_in[11];
    const float* v1  = (const float*)d_in[12];
    const float* g2  = (const float*)d_in[13];
    const float* be2 = (const float*)d_in[14];
    const float* m2  = (const float*)d_in[15];
    const float* v2  = (const float*)d_in[16];
    const float* g3  = (const float*)d_in[17];
    const float* be3 = (const float*)d_in[18];
    const float* m3  = (const float*)d_in[19];
    const float* v3  = (const float*)d_in[20];
    const float* Wm1 = (const float*)d_in[21];
    const float* bm1 = (const float*)d_in[22];
    const float* Wm2 = (const float*)d_in[23];
    const float* bm2 = (const float*)d_in[24];
    float* outp = (float*)d_out;

    const int Nn = in_sizes[0] / 128;
    const int E  = in_sizes[1] / 2;
    const int G  = 128;
    const int* srcv = edge;
    const int* dstv = edge + E;

    float* ws   = (float*)d_ws;
    float* bufA = ws;                               // Nn*128
    float* bufB = bufA + (size_t)Nn * 128;          // Nn*128
    float* dinv = bufB + (size_t)Nn * 128;          // Nn
    float* norm = dinv + Nn;                        // E
    int*   start = (int*)(norm + E);                // G+1

    const int TB = 256;

    // prep: degrees (self-loop => init 1), dinv, per-edge norm, graph boundaries
    fill_kernel<<<cdiv(Nn, TB), TB, 0, stream>>>(dinv, 1.0f, Nn);
    deg_kernel<<<cdiv(E, TB), TB, 0, stream>>>(dstv, dinv, E);
    dinv_kernel<<<cdiv(Nn, TB), TB, 0, stream>>>(dinv, Nn);
    norm_kernel<<<cdiv(E, TB), TB, 0, stream>>>(srcv, dstv, dinv, norm, E);
    boundary_kernel<<<cdiv(Nn, TB), TB, 0, stream>>>(batch, start, Nn, G);

    // ---- layer 1: h = x @ W1 (128->128); aggregate; finalize ----
    gemm_f32<64, 128, 32, 8, 4, 128, 128><<<cdiv(Nn, 64), 256, 0, stream>>>(x, W1, bufA, Nn);
    hipMemsetAsync(bufB, 0, (size_t)Nn * 128 * sizeof(float), stream);
    agg_kernel<128><<<cdiv(E * 32, TB), TB, 0, stream>>>(bufA, bufB, srcv, dstv, norm, E);
    finalize_kernel<128><<<cdiv(Nn * 32, TB), TB, 0, stream>>>(bufA, bufB, dinv, b1, g1, be1, m1, v1, Nn);

    // ---- layer 2: h = h1 @ W2 (128->64) ----
    gemm_f32<128, 64, 32, 8, 4, 128, 64><<<cdiv(Nn, 128), 256, 0, stream>>>(bufA, W2, bufB, Nn);
    hipMemsetAsync(bufA, 0, (size_t)Nn * 64 * sizeof(float), stream);
    agg_kernel<64><<<cdiv(E * 16, TB), TB, 0, stream>>>(bufB, bufA, srcv, dstv, norm, E);
    finalize_kernel<64><<<cdiv(Nn * 16, TB), TB, 0, stream>>>(bufB, bufA, dinv, b2, g2, be2, m2, v2, Nn);

    // ---- layer 3: h = h2 @ W3 (64->64) ----
    gemm_f32<128, 64, 32, 8, 4, 64, 64><<<cdiv(Nn, 128), 256, 0, stream>>>(bufB, W3, bufA, Nn);
    hipMemsetAsync(bufB, 0, (size_t)Nn * 64 * sizeof(float), stream);
    agg_kernel<64><<<cdiv(E * 16, TB), TB, 0, stream>>>(bufA, bufB, srcv, dstv, norm, E);
    finalize_kernel<64><<<cdiv(Nn * 16, TB), TB, 0, stream>>>(bufA, bufB, dinv, b3, g3, be3, m3, v3, Nn);

    // ---- pool + MLP ----
    pool_mlp_kernel<<<G, 64, 0, stream>>>(bufA, start, Wm1, bm1, Wm2, bm2, outp);
}

// Round 4
// 981.192 us; speedup vs baseline: 5.9505x; 5.9505x over previous
//
#include <hip/hip_runtime.h>
#include <math.h>

#define BN_EPS 1e-5f

// ---------------- CSR build: count / scan / scatter ----------------

__global__ void count_kernel(const int* __restrict__ dstv, int* __restrict__ cnt, int E) {
    int e = blockIdx.x * blockDim.x + threadIdx.x;
    if (e < E) atomicAdd(&cnt[dstv[e]], 1);
}

__global__ void dinv_kernel(const int* __restrict__ cnt, float* __restrict__ dinv, int n) {
    int i = blockIdx.x * blockDim.x + threadIdx.x;
    if (i < n) dinv[i] = rsqrtf((float)cnt[i] + 1.0f);  // +1 self-loop
}

// per-block exclusive scan; writes block-local exclusive + block total
__global__ void scan_block_kernel(const int* __restrict__ cnt, int* __restrict__ out,
                                  int* __restrict__ bsum, int Nn) {
    __shared__ int s[256];
    int t = threadIdx.x;
    int i = blockIdx.x * 256 + t;
    int v = (i < Nn) ? cnt[i] : 0;
    s[t] = v;
    __syncthreads();
    for (int off = 1; off < 256; off <<= 1) {
        int add = (t >= off) ? s[t - off] : 0;
        __syncthreads();
        s[t] += add;
        __syncthreads();
    }
    if (i < Nn) out[i] = s[t] - v;           // exclusive
    if (t == 255) bsum[blockIdx.x] = s[255]; // inclusive total
}

__global__ void scan_sums_kernel(int* __restrict__ bsum, int nb) {
    __shared__ int s[512];
    int t = threadIdx.x;
    int v = (t < nb) ? bsum[t] : 0;
    s[t] = v;
    __syncthreads();
    for (int off = 1; off < 512; off <<= 1) {
        int add = (t >= off) ? s[t - off] : 0;
        __syncthreads();
        s[t] += add;
        __syncthreads();
    }
    if (t < nb) bsum[t] = s[t] - v;          // exclusive
}

__global__ void add_offsets_kernel(int* __restrict__ row_ptr, const int* __restrict__ bsum,
                                   int Nn, int E) {
    int i = blockIdx.x * 256 + threadIdx.x;
    if (i < Nn) row_ptr[i] += bsum[blockIdx.x];
    if (i == 0) row_ptr[Nn] = E;
}

__global__ void copy_pos_kernel(const int* __restrict__ row_ptr, int* __restrict__ pos, int Nn) {
    int i = blockIdx.x * blockDim.x + threadIdx.x;
    if (i < Nn) pos[i] = row_ptr[i];
}

__global__ void scatter_kernel(const int* __restrict__ srcv, const int* __restrict__ dstv,
                               int* __restrict__ pos, int* __restrict__ col, int E) {
    int e = blockIdx.x * blockDim.x + threadIdx.x;
    if (e < E) {
        int p = atomicAdd(&pos[dstv[e]], 1);
        col[p] = srcv[e];
    }
}

// batch is sorted; start[g] = first node of graph g, start[G] = N
__global__ void boundary_kernel(const int* __restrict__ batch, int* __restrict__ start,
                                int Nn, int G) {
    int i = blockIdx.x * blockDim.x + threadIdx.x;
    if (i >= Nn) return;
    int b = batch[i];
    if (i == 0) {
        for (int g = 0; g <= b; ++g) start[g] = 0;
    } else {
        int p = batch[i - 1];
        for (int g = p + 1; g <= b; ++g) start[g] = i;
    }
    if (i == Nn - 1) {
        for (int g = b + 1; g <= G; ++g) start[g] = Nn;
    }
}

// ---------------- f32 tiled GEMM: C[M,N] = A[M,K] @ W[K,N] ----------------

template<int BM, int BN, int BK, int TM, int TN, int K, int N>
__global__ __launch_bounds__(256)
void gemm_f32(const float* __restrict__ A, const float* __restrict__ W,
              float* __restrict__ C, int M) {
    constexpr int THREADS = (BM / TM) * (BN / TN);
    static_assert(THREADS == 256, "bad tile config");
    __shared__ float As[BK][BM + 4];
    __shared__ float Ws[BK][BN];
    const int tid  = threadIdx.x;
    const int tcol = tid % (BN / TN);
    const int trow = tid / (BN / TN);
    const int r0   = blockIdx.x * BM;

    float acc[TM][TN] = {};

    constexpr int A_LD4 = BM * BK / 4 / THREADS;
    constexpr int W_LD4 = BK * BN / 4 / THREADS;

    for (int kt = 0; kt < K; kt += BK) {
        #pragma unroll
        for (int t = 0; t < A_LD4; ++t) {
            int idx = t * THREADS + tid;
            int row = idx / (BK / 4);
            int kq  = idx % (BK / 4);
            int gr  = r0 + row; if (gr >= M) gr = M - 1;
            float4 v = *(const float4*)&A[(size_t)gr * K + kt + kq * 4];
            As[kq * 4 + 0][row] = v.x;
            As[kq * 4 + 1][row] = v.y;
            As[kq * 4 + 2][row] = v.z;
            As[kq * 4 + 3][row] = v.w;
        }
        #pragma unroll
        for (int t = 0; t < W_LD4; ++t) {
            int idx = t * THREADS + tid;
            int kr = idx / (BN / 4);
            int nc = idx % (BN / 4);
            *(float4*)&Ws[kr][nc * 4] = *(const float4*)&W[(size_t)(kt + kr) * N + nc * 4];
        }
        __syncthreads();
        #pragma unroll
        for (int kk = 0; kk < BK; ++kk) {
            float a[TM], b[TN];
            #pragma unroll
            for (int m = 0; m < TM; m += 4) {
                float4 v = *(const float4*)&As[kk][trow * TM + m];
                a[m] = v.x; a[m+1] = v.y; a[m+2] = v.z; a[m+3] = v.w;
            }
            #pragma unroll
            for (int n = 0; n < TN; n += 4) {
                float4 v = *(const float4*)&Ws[kk][tcol * TN + n];
                b[n] = v.x; b[n+1] = v.y; b[n+2] = v.z; b[n+3] = v.w;
            }
            #pragma unroll
            for (int m = 0; m < TM; ++m)
                #pragma unroll
                for (int n = 0; n < TN; ++n)
                    acc[m][n] = fmaf(a[m], b[n], acc[m][n]);
        }
        __syncthreads();
    }
    #pragma unroll
    for (int m = 0; m < TM; ++m) {
        int gr = r0 + trow * TM + m;
        if (gr < M) {
            float4 v = { acc[m][0], acc[m][1], acc[m][2], acc[m][3] };
            *(float4*)&C[(size_t)gr * N + tcol * TN] = v;
        }
    }
}

// ---------------- fused gather-aggregate + self-loop + bias + BN + ReLU ----------------
// out[i,c] = relu( BN( dinv[i] * sum_{s in N(i)} dinv[s]*t[s,c] + dinv[i]^2*t[i,c] + bias[c] ) )
// one wave (64 lanes) per node; lane handles channels {v*64+lane}

template<int C>
__global__ __launch_bounds__(256)
void gcn_gather(const float* __restrict__ t, float* __restrict__ out,
                const int* __restrict__ row_ptr, const int* __restrict__ col,
                const float* __restrict__ dinv,
                const float* __restrict__ bias,
                const float* __restrict__ gam, const float* __restrict__ bet,
                const float* __restrict__ mu,  const float* __restrict__ var,
                int Nn) {
    constexpr int V = C / 64;
    int wid  = (int)((blockIdx.x * 256 + threadIdx.x) >> 6);  // node id
    int lane = threadIdx.x & 63;
    if (wid >= Nn) return;

    int b0 = row_ptr[wid];
    int b1 = row_ptr[wid + 1];
    float di = dinv[wid];

    float acc[V] = {};

    int e = b0;
    int sN = (e < b1) ? col[e] : 0;   // prefetch
    while (e < b1) {
        int s = sN;
        ++e;
        sN = (e < b1) ? col[e] : 0;   // overlap next col load with feature gather
        float ds = dinv[s];
        #pragma unroll
        for (int v = 0; v < V; ++v)
            acc[v] += ds * t[(size_t)s * C + v * 64 + lane];
    }

    float d2 = di * di;
    #pragma unroll
    for (int v = 0; v < V; ++v) {
        int c = v * 64 + lane;
        float tv = t[(size_t)wid * C + c];
        float sc = gam[c] * rsqrtf(var[c] + BN_EPS);
        float sh = bet[c] - mu[c] * sc;
        float h  = di * acc[v] + d2 * tv + bias[c];
        out[(size_t)wid * C + c] = fmaxf(h * sc + sh, 0.0f);
    }
}

// ---------------- pool + MLP head ----------------

__global__ __launch_bounds__(64)
void pool_mlp_kernel(const float* __restrict__ h3, const int* __restrict__ start,
                     const float* __restrict__ Wm1, const float* __restrict__ bm1,
                     const float* __restrict__ Wm2, const float* __restrict__ bm2,
                     float* __restrict__ out) {
    int g = blockIdx.x;
    int c = threadIdx.x;  // 64
    int s = start[g], e = start[g + 1];
    float sum = 0.0f;
    for (int i = s; i < e; ++i) sum += h3[(size_t)i * 64 + c];
    float cnt = (float)(e - s);
    float pooled = sum / fmaxf(cnt, 1.0f);
    __shared__ float pl[64];
    __shared__ float zl[64];
    pl[c] = pooled;
    __syncthreads();
    float z = bm1[c];
    for (int j = 0; j < 64; ++j) z = fmaf(pl[j], Wm1[j * 64 + c], z);
    z = fmaxf(z, 0.0f);
    zl[c] = z;
    __syncthreads();
    if (c < 10) {
        float o = bm2[c];
        for (int j = 0; j < 64; ++j) o = fmaf(zl[j], Wm2[j * 10 + c], o);
        out[g * 10 + c] = o;
    }
}

// ---------------- launcher ----------------

static inline int cdiv(int a, int b) { return (a + b - 1) / b; }

extern "C" void kernel_launch(void* const* d_in, const int* in_sizes, int n_in,
                              void* d_out, int out_size, void* d_ws, size_t ws_size,
                              hipStream_t stream) {
    const float* x   = (const float*)d_in[0];
    const int* edge  = (const int*)d_in[1];
    const int* batch = (const int*)d_in[2];
    const float* W1  = (const float*)d_in[3];
    const float* b1  = (const float*)d_in[4];
    const float* W2  = (const float*)d_in[5];
    const float* b2  = (const float*)d_in[6];
    const float* W3  = (const float*)d_in[7];
    const float* b3  = (const float*)d_in[8];
    const float* g1  = (const float*)d_in[9];
    const float* be1 = (const float*)d_in[10];
    const float* m1  = (const float*)d_in[11];
    const float* v1  = (const float*)d_in[12];
    const float* g2  = (const float*)d_in[13];
    const float* be2 = (const float*)d_in[14];
    const float* m2  = (const float*)d_in[15];
    const float* v2  = (const float*)d_in[16];
    const float* g3  = (const float*)d_in[17];
    const float* be3 = (const float*)d_in[18];
    const float* m3  = (const float*)d_in[19];
    const float* v3  = (const float*)d_in[20];
    const float* Wm1 = (const float*)d_in[21];
    const float* bm1 = (const float*)d_in[22];
    const float* Wm2 = (const float*)d_in[23];
    const float* bm2 = (const float*)d_in[24];
    float* outp = (float*)d_out;

    const int Nn = in_sizes[0] / 128;
    const int E  = in_sizes[1] / 2;
    const int G  = 128;
    const int* srcv = edge;
    const int* dstv = edge + E;

    // ws layout (floats): bufA(Nn*128) | bufB(Nn*128) | dinv(Nn) | row_ptr(Nn+1) | col(E) | start(G+1)
    float* ws     = (float*)d_ws;
    float* bufA   = ws;
    float* bufB   = bufA + (size_t)Nn * 128;
    float* dinv   = bufB + (size_t)Nn * 128;
    int*   row_ptr = (int*)(dinv + Nn);
    int*   col    = row_ptr + (Nn + 1);
    int*   start  = col + E;

    // transient ints overlaid on bufA (free until GEMM1 writes it)
    int* cnt  = (int*)bufA;            // Nn
    int* pos  = cnt + Nn;              // Nn
    int* bsum = pos + Nn;              // cdiv(Nn,256)

    const int TB = 256;
    const int nb = cdiv(Nn, 256);

    // ---- CSR build + norms + graph boundaries ----
    hipMemsetAsync(cnt, 0, (size_t)Nn * sizeof(int), stream);
    count_kernel<<<cdiv(E, TB), TB, 0, stream>>>(dstv, cnt, E);
    dinv_kernel<<<cdiv(Nn, TB), TB, 0, stream>>>(cnt, dinv, Nn);
    scan_block_kernel<<<nb, 256, 0, stream>>>(cnt, row_ptr, bsum, Nn);
    scan_sums_kernel<<<1, 512, 0, stream>>>(bsum, nb);
    add_offsets_kernel<<<nb, 256, 0, stream>>>(row_ptr, bsum, Nn, E);
    copy_pos_kernel<<<cdiv(Nn, TB), TB, 0, stream>>>(row_ptr, pos, Nn);
    scatter_kernel<<<cdiv(E, TB), TB, 0, stream>>>(srcv, dstv, pos, col, E);
    boundary_kernel<<<cdiv(Nn, TB), TB, 0, stream>>>(batch, start, Nn, G);

    // ---- layer 1: t = x @ W1 (128->128); fused gather+BN+ReLU -> bufB ----
    gemm_f32<64, 128, 32, 8, 4, 128, 128><<<cdiv(Nn, 64), 256, 0, stream>>>(x, W1, bufA, Nn);
    gcn_gather<128><<<cdiv(Nn, 4), 256, 0, stream>>>(bufA, bufB, row_ptr, col, dinv,
                                                     b1, g1, be1, m1, v1, Nn);

    // ---- layer 2: t = h1 @ W2 (128->64) ----
    gemm_f32<128, 64, 32, 8, 4, 128, 64><<<cdiv(Nn, 128), 256, 0, stream>>>(bufB, W2, bufA, Nn);
    gcn_gather<64><<<cdiv(Nn, 4), 256, 0, stream>>>(bufA, bufB, row_ptr, col, dinv,
                                                    b2, g2, be2, m2, v2, Nn);

    // ---- layer 3: t = h2 @ W3 (64->64) ----
    gemm_f32<128, 64, 32, 8, 4, 64, 64><<<cdiv(Nn, 128), 256, 0, stream>>>(bufB, W3, bufA, Nn);
    gcn_gather<64><<<cdiv(Nn, 4), 256, 0, stream>>>(bufA, bufB, row_ptr, col, dinv,
                                                    b3, g3, be3, m3, v3, Nn);

    // ---- pool + MLP ----
    pool_mlp_kernel<<<G, 64, 0, stream>>>(bufB, start, Wm1, bm1, Wm2, bm2, outp);
}

// Round 5
// 812.882 us; speedup vs baseline: 7.1825x; 1.2071x over previous
//
#include <hip/hip_runtime.h>
#include <math.h>

#define BN_EPS 1e-5f

// ---------------- CSR build: count / scan / scatter ----------------

__global__ void count_kernel(const int* __restrict__ dstv, int* __restrict__ cnt, int E) {
    int e = blockIdx.x * blockDim.x + threadIdx.x;
    if (e < E) atomicAdd(&cnt[dstv[e]], 1);
}

__global__ void dinv_kernel(const int* __restrict__ cnt, float* __restrict__ dinv, int n) {
    int i = blockIdx.x * blockDim.x + threadIdx.x;
    if (i < n) dinv[i] = rsqrtf((float)cnt[i] + 1.0f);  // +1 self-loop
}

// per-block exclusive scan; writes block-local exclusive + block total
__global__ void scan_block_kernel(const int* __restrict__ cnt, int* __restrict__ out,
                                  int* __restrict__ bsum, int Nn) {
    __shared__ int s[256];
    int t = threadIdx.x;
    int i = blockIdx.x * 256 + t;
    int v = (i < Nn) ? cnt[i] : 0;
    s[t] = v;
    __syncthreads();
    for (int off = 1; off < 256; off <<= 1) {
        int add = (t >= off) ? s[t - off] : 0;
        __syncthreads();
        s[t] += add;
        __syncthreads();
    }
    if (i < Nn) out[i] = s[t] - v;           // exclusive
    if (t == 255) bsum[blockIdx.x] = s[255]; // inclusive total
}

__global__ void scan_sums_kernel(int* __restrict__ bsum, int nb) {
    __shared__ int s[512];
    int t = threadIdx.x;
    int v = (t < nb) ? bsum[t] : 0;
    s[t] = v;
    __syncthreads();
    for (int off = 1; off < 512; off <<= 1) {
        int add = (t >= off) ? s[t - off] : 0;
        __syncthreads();
        s[t] += add;
        __syncthreads();
    }
    if (t < nb) bsum[t] = s[t] - v;          // exclusive
}

__global__ void add_offsets_kernel(int* __restrict__ row_ptr, const int* __restrict__ bsum,
                                   int Nn, int E) {
    int i = blockIdx.x * 256 + threadIdx.x;
    if (i < Nn) row_ptr[i] += bsum[blockIdx.x];
    if (i == 0) row_ptr[Nn] = E;
}

__global__ void copy_pos_kernel(const int* __restrict__ row_ptr, int* __restrict__ pos, int Nn) {
    int i = blockIdx.x * blockDim.x + threadIdx.x;
    if (i < Nn) pos[i] = row_ptr[i];
}

__global__ void scatter_kernel(const int* __restrict__ srcv, const int* __restrict__ dstv,
                               int* __restrict__ pos, int* __restrict__ col, int E) {
    int e = blockIdx.x * blockDim.x + threadIdx.x;
    if (e < E) {
        int p = atomicAdd(&pos[dstv[e]], 1);
        col[p] = srcv[e];
    }
}

// batch is sorted; start[g] = first node of graph g, start[G] = N
__global__ void boundary_kernel(const int* __restrict__ batch, int* __restrict__ start,
                                int Nn, int G) {
    int i = blockIdx.x * blockDim.x + threadIdx.x;
    if (i >= Nn) return;
    int b = batch[i];
    if (i == 0) {
        for (int g = 0; g <= b; ++g) start[g] = 0;
    } else {
        int p = batch[i - 1];
        for (int g = p + 1; g <= b; ++g) start[g] = i;
    }
    if (i == Nn - 1) {
        for (int g = b + 1; g <= G; ++g) start[g] = Nn;
    }
}

// ---------------- f32 tiled GEMM: C[M,N] = A[M,K] @ W[K,N] ----------------

template<int BM, int BN, int BK, int TM, int TN, int K, int N>
__global__ __launch_bounds__(256)
void gemm_f32(const float* __restrict__ A, const float* __restrict__ W,
              float* __restrict__ C, int M) {
    constexpr int THREADS = (BM / TM) * (BN / TN);
    static_assert(THREADS == 256, "bad tile config");
    __shared__ float As[BK][BM + 4];
    __shared__ float Ws[BK][BN];
    const int tid  = threadIdx.x;
    const int tcol = tid % (BN / TN);
    const int trow = tid / (BN / TN);
    const int r0   = blockIdx.x * BM;

    float acc[TM][TN] = {};

    constexpr int A_LD4 = BM * BK / 4 / THREADS;
    constexpr int W_LD4 = BK * BN / 4 / THREADS;

    for (int kt = 0; kt < K; kt += BK) {
        #pragma unroll
        for (int t = 0; t < A_LD4; ++t) {
            int idx = t * THREADS + tid;
            int row = idx / (BK / 4);
            int kq  = idx % (BK / 4);
            int gr  = r0 + row; if (gr >= M) gr = M - 1;
            float4 v = *(const float4*)&A[(size_t)gr * K + kt + kq * 4];
            As[kq * 4 + 0][row] = v.x;
            As[kq * 4 + 1][row] = v.y;
            As[kq * 4 + 2][row] = v.z;
            As[kq * 4 + 3][row] = v.w;
        }
        #pragma unroll
        for (int t = 0; t < W_LD4; ++t) {
            int idx = t * THREADS + tid;
            int kr = idx / (BN / 4);
            int nc = idx % (BN / 4);
            *(float4*)&Ws[kr][nc * 4] = *(const float4*)&W[(size_t)(kt + kr) * N + nc * 4];
        }
        __syncthreads();
        #pragma unroll
        for (int kk = 0; kk < BK; ++kk) {
            float a[TM], b[TN];
            #pragma unroll
            for (int m = 0; m < TM; m += 4) {
                float4 v = *(const float4*)&As[kk][trow * TM + m];
                a[m] = v.x; a[m+1] = v.y; a[m+2] = v.z; a[m+3] = v.w;
            }
            #pragma unroll
            for (int n = 0; n < TN; n += 4) {
                float4 v = *(const float4*)&Ws[kk][tcol * TN + n];
                b[n] = v.x; b[n+1] = v.y; b[n+2] = v.z; b[n+3] = v.w;
            }
            #pragma unroll
            for (int m = 0; m < TM; ++m)
                #pragma unroll
                for (int n = 0; n < TN; ++n)
                    acc[m][n] = fmaf(a[m], b[n], acc[m][n]);
        }
        __syncthreads();
    }
    #pragma unroll
    for (int m = 0; m < TM; ++m) {
        int gr = r0 + trow * TM + m;
        if (gr < M) {
            float4 v = { acc[m][0], acc[m][1], acc[m][2], acc[m][3] };
            *(float4*)&C[(size_t)gr * N + tcol * TN] = v;
        }
    }
}

// ---------------- fused gather-aggregate + self-loop + bias + BN + ReLU ----------------
// out[i,c] = relu( BN( dinv[i] * sum_{s in N(i)} dinv[s]*t[s,c] + dinv[i]^2*t[i,c] + bias[c] ) )
// one wave (64 lanes) per node; lane handles channels {v*64+lane}

template<int C>
__global__ __launch_bounds__(256)
void gcn_gather(const float* __restrict__ t, float* __restrict__ out,
                const int* __restrict__ row_ptr, const int* __restrict__ col,
                const float* __restrict__ dinv,
                const float* __restrict__ bias,
                const float* __restrict__ gam, const float* __restrict__ bet,
                const float* __restrict__ mu,  const float* __restrict__ var,
                int Nn) {
    constexpr int V = C / 64;
    int wid  = (int)((blockIdx.x * 256 + threadIdx.x) >> 6);  // node id
    int lane = threadIdx.x & 63;
    if (wid >= Nn) return;

    int b0 = row_ptr[wid];
    int b1 = row_ptr[wid + 1];
    float di = dinv[wid];

    float acc[V] = {};

    int e = b0;
    int sN = (e < b1) ? col[e] : 0;   // prefetch
    while (e < b1) {
        int s = sN;
        ++e;
        sN = (e < b1) ? col[e] : 0;   // overlap next col load with feature gather
        float ds = dinv[s];
        #pragma unroll
        for (int v = 0; v < V; ++v)
            acc[v] += ds * t[(size_t)s * C + v * 64 + lane];
    }

    float d2 = di * di;
    #pragma unroll
    for (int v = 0; v < V; ++v) {
        int c = v * 64 + lane;
        float tv = t[(size_t)wid * C + c];
        float sc = gam[c] * rsqrtf(var[c] + BN_EPS);
        float sh = bet[c] - mu[c] * sc;
        float h  = di * acc[v] + d2 * tv + bias[c];
        out[(size_t)wid * C + c] = fmaxf(h * sc + sh, 0.0f);
    }
}

// ---------------- parallel pool: wave per 64-node chunk, lane = channel ----------------
// batch sorted; register-accumulate per graph run, atomic flush at boundaries.

__global__ __launch_bounds__(256)
void pool_sum_kernel(const float* __restrict__ h3, const int* __restrict__ batch,
                     float* __restrict__ sums, int Nn) {
    int wid  = (int)((blockIdx.x * 256 + threadIdx.x) >> 6);
    int lane = threadIdx.x & 63;
    int i0 = wid * 64;
    if (i0 >= Nn) return;
    int i1 = i0 + 64; if (i1 > Nn) i1 = Nn;

    float acc = 0.0f;
    int g = batch[i0];
    for (int i = i0; i < i1; ++i) {
        int gi = batch[i];
        if (gi != g) {
            unsafeAtomicAdd(&sums[g * 64 + lane], acc);
            acc = 0.0f;
            g = gi;
        }
        acc += h3[(size_t)i * 64 + lane];
    }
    unsafeAtomicAdd(&sums[g * 64 + lane], acc);
}

// ---------------- MLP head on pooled sums ----------------

__global__ __launch_bounds__(64)
void mlp_kernel(const float* __restrict__ sums, const int* __restrict__ start,
                const float* __restrict__ Wm1, const float* __restrict__ bm1,
                const float* __restrict__ Wm2, const float* __restrict__ bm2,
                float* __restrict__ out) {
    int g = blockIdx.x;
    int c = threadIdx.x;  // 64
    float cnt = (float)(start[g + 1] - start[g]);
    float pooled = sums[g * 64 + c] / fmaxf(cnt, 1.0f);
    __shared__ float pl[64];
    __shared__ float zl[64];
    pl[c] = pooled;
    __syncthreads();
    float z = bm1[c];
    for (int j = 0; j < 64; ++j) z = fmaf(pl[j], Wm1[j * 64 + c], z);
    z = fmaxf(z, 0.0f);
    zl[c] = z;
    __syncthreads();
    if (c < 10) {
        float o = bm2[c];
        for (int j = 0; j < 64; ++j) o = fmaf(zl[j], Wm2[j * 10 + c], o);
        out[g * 10 + c] = o;
    }
}

// ---------------- launcher ----------------

static inline int cdiv(int a, int b) { return (a + b - 1) / b; }

extern "C" void kernel_launch(void* const* d_in, const int* in_sizes, int n_in,
                              void* d_out, int out_size, void* d_ws, size_t ws_size,
                              hipStream_t stream) {
    const float* x   = (const float*)d_in[0];
    const int* edge  = (const int*)d_in[1];
    const int* batch = (const int*)d_in[2];
    const float* W1  = (const float*)d_in[3];
    const float* b1  = (const float*)d_in[4];
    const float* W2  = (const float*)d_in[5];
    const float* b2  = (const float*)d_in[6];
    const float* W3  = (const float*)d_in[7];
    const float* b3  = (const float*)d_in[8];
    const float* g1  = (const float*)d_in[9];
    const float* be1 = (const float*)d_in[10];
    const float* m1  = (const float*)d_in[11];
    const float* v1  = (const float*)d_in[12];
    const float* g2  = (const float*)d_in[13];
    const float* be2 = (const float*)d_in[14];
    const float* m2  = (const float*)d_in[15];
    const float* v2  = (const float*)d_in[16];
    const float* g3  = (const float*)d_in[17];
    const float* be3 = (const float*)d_in[18];
    const float* m3  = (const float*)d_in[19];
    const float* v3  = (const float*)d_in[20];
    const float* Wm1 = (const float*)d_in[21];
    const float* bm1 = (const float*)d_in[22];
    const float* Wm2 = (const float*)d_in[23];
    const float* bm2 = (const float*)d_in[24];
    float* outp = (float*)d_out;

    const int Nn = in_sizes[0] / 128;
    const int E  = in_sizes[1] / 2;
    const int G  = 128;
    const int* srcv = edge;
    const int* dstv = edge + E;

    // ws layout (floats): bufA(Nn*128) | bufB(Nn*128) | dinv(Nn) | row_ptr(Nn+1) | col(E) | start(G+1) | sums(G*64)
    float* ws     = (float*)d_ws;
    float* bufA   = ws;
    float* bufB   = bufA + (size_t)Nn * 128;
    float* dinv   = bufB + (size_t)Nn * 128;
    int*   row_ptr = (int*)(dinv + Nn);
    int*   col    = row_ptr + (Nn + 1);
    int*   start  = col + E;
    float* sums   = (float*)(start + (G + 1));

    // transient ints overlaid on bufA (free until GEMM1 writes it)
    int* cnt  = (int*)bufA;            // Nn
    int* pos  = cnt + Nn;              // Nn
    int* bsum = pos + Nn;              // cdiv(Nn,256)

    const int TB = 256;
    const int nb = cdiv(Nn, 256);

    // ---- CSR build + norms + graph boundaries ----
    hipMemsetAsync(cnt, 0, (size_t)Nn * sizeof(int), stream);
    count_kernel<<<cdiv(E, TB), TB, 0, stream>>>(dstv, cnt, E);
    dinv_kernel<<<cdiv(Nn, TB), TB, 0, stream>>>(cnt, dinv, Nn);
    scan_block_kernel<<<nb, 256, 0, stream>>>(cnt, row_ptr, bsum, Nn);
    scan_sums_kernel<<<1, 512, 0, stream>>>(bsum, nb);
    add_offsets_kernel<<<nb, 256, 0, stream>>>(row_ptr, bsum, Nn, E);
    copy_pos_kernel<<<cdiv(Nn, TB), TB, 0, stream>>>(row_ptr, pos, Nn);
    scatter_kernel<<<cdiv(E, TB), TB, 0, stream>>>(srcv, dstv, pos, col, E);
    boundary_kernel<<<cdiv(Nn, TB), TB, 0, stream>>>(batch, start, Nn, G);

    // ---- layer 1: t = x @ W1 (128->128); fused gather+BN+ReLU -> bufB ----
    gemm_f32<64, 128, 32, 8, 4, 128, 128><<<cdiv(Nn, 64), 256, 0, stream>>>(x, W1, bufA, Nn);
    gcn_gather<128><<<cdiv(Nn, 4), 256, 0, stream>>>(bufA, bufB, row_ptr, col, dinv,
                                                     b1, g1, be1, m1, v1, Nn);

    // ---- layer 2: t = h1 @ W2 (128->64) ----
    gemm_f32<128, 64, 32, 8, 4, 128, 64><<<cdiv(Nn, 128), 256, 0, stream>>>(bufB, W2, bufA, Nn);
    gcn_gather<64><<<cdiv(Nn, 4), 256, 0, stream>>>(bufA, bufB, row_ptr, col, dinv,
                                                    b2, g2, be2, m2, v2, Nn);

    // ---- layer 3: t = h2 @ W3 (64->64) ----
    gemm_f32<128, 64, 32, 8, 4, 64, 64><<<cdiv(Nn, 128), 256, 0, stream>>>(bufB, W3, bufA, Nn);
    gcn_gather<64><<<cdiv(Nn, 4), 256, 0, stream>>>(bufA, bufB, row_ptr, col, dinv,
                                                    b3, g3, be3, m3, v3, Nn);

    // ---- pool + MLP ----
    hipMemsetAsync(sums, 0, (size_t)G * 64 * sizeof(float), stream);
    pool_sum_kernel<<<cdiv(Nn, 256), 256, 0, stream>>>(bufB, batch, sums, Nn);
    mlp_kernel<<<G, 64, 0, stream>>>(sums, start, Wm1, bm1, Wm2, bm2, outp);
}

// Round 6
// 620.984 us; speedup vs baseline: 9.4021x; 1.3090x over previous
//
#include <hip/hip_runtime.h>
#include <math.h>

#define BN_EPS 1e-5f

// ---------------- CSR build: count / scan / scatter ----------------

__global__ void count_kernel(const int* __restrict__ dstv, int* __restrict__ cnt, int E) {
    int e = blockIdx.x * blockDim.x + threadIdx.x;
    if (e < E) atomicAdd(&cnt[dstv[e]], 1);
}

__global__ void dinv_kernel(const int* __restrict__ cnt, float* __restrict__ dinv, int n) {
    int i = blockIdx.x * blockDim.x + threadIdx.x;
    if (i < n) dinv[i] = rsqrtf((float)cnt[i] + 1.0f);  // +1 self-loop
}

// per-block exclusive scan; writes block-local exclusive + block total
__global__ void scan_block_kernel(const int* __restrict__ cnt, int* __restrict__ out,
                                  int* __restrict__ bsum, int Nn) {
    __shared__ int s[256];
    int t = threadIdx.x;
    int i = blockIdx.x * 256 + t;
    int v = (i < Nn) ? cnt[i] : 0;
    s[t] = v;
    __syncthreads();
    for (int off = 1; off < 256; off <<= 1) {
        int add = (t >= off) ? s[t - off] : 0;
        __syncthreads();
        s[t] += add;
        __syncthreads();
    }
    if (i < Nn) out[i] = s[t] - v;           // exclusive
    if (t == 255) bsum[blockIdx.x] = s[255]; // inclusive total
}

__global__ void scan_sums_kernel(int* __restrict__ bsum, int nb) {
    __shared__ int s[512];
    int t = threadIdx.x;
    int v = (t < nb) ? bsum[t] : 0;
    s[t] = v;
    __syncthreads();
    for (int off = 1; off < 512; off <<= 1) {
        int add = (t >= off) ? s[t - off] : 0;
        __syncthreads();
        s[t] += add;
        __syncthreads();
    }
    if (t < nb) bsum[t] = s[t] - v;          // exclusive
}

// adds block offsets AND initializes pos[] (merged copy_pos)
__global__ void add_offsets_kernel(int* __restrict__ row_ptr, const int* __restrict__ bsum,
                                   int* __restrict__ pos, int Nn, int E) {
    int i = blockIdx.x * 256 + threadIdx.x;
    if (i < Nn) {
        int v = row_ptr[i] + bsum[blockIdx.x];
        row_ptr[i] = v;
        pos[i] = v;
    }
    if (i == 0) row_ptr[Nn] = E;
}

// scatter edge -> CSR slot; also store wnorm[p] = dinv[src] (breaks the
// col->dinv dependent chain in the gather hot loop)
__global__ void scatter_kernel(const int* __restrict__ srcv, const int* __restrict__ dstv,
                               const float* __restrict__ dinv,
                               int* __restrict__ pos, int* __restrict__ col,
                               float* __restrict__ wnorm, int E) {
    int e = blockIdx.x * blockDim.x + threadIdx.x;
    if (e < E) {
        int s = srcv[e];
        int p = atomicAdd(&pos[dstv[e]], 1);
        col[p] = s;
        wnorm[p] = dinv[s];
    }
}

// batch is sorted; start[g] = first node of graph g, start[G] = N
__global__ void boundary_kernel(const int* __restrict__ batch, int* __restrict__ start,
                                int Nn, int G) {
    int i = blockIdx.x * blockDim.x + threadIdx.x;
    if (i >= Nn) return;
    int b = batch[i];
    if (i == 0) {
        for (int g = 0; g <= b; ++g) start[g] = 0;
    } else {
        int p = batch[i - 1];
        for (int g = p + 1; g <= b; ++g) start[g] = i;
    }
    if (i == Nn - 1) {
        for (int g = b + 1; g <= G; ++g) start[g] = Nn;
    }
}

// ---------------- f32 tiled GEMM: C[M,N] = A[M,K] @ W[K,N] ----------------

template<int BM, int BN, int BK, int TM, int TN, int K, int N>
__global__ __launch_bounds__(256)
void gemm_f32(const float* __restrict__ A, const float* __restrict__ W,
              float* __restrict__ C, int M) {
    constexpr int THREADS = (BM / TM) * (BN / TN);
    static_assert(THREADS == 256, "bad tile config");
    __shared__ float As[BK][BM + 4];
    __shared__ float Ws[BK][BN];
    const int tid  = threadIdx.x;
    const int tcol = tid % (BN / TN);
    const int trow = tid / (BN / TN);
    const int r0   = blockIdx.x * BM;

    float acc[TM][TN] = {};

    constexpr int A_LD4 = BM * BK / 4 / THREADS;
    constexpr int W_LD4 = BK * BN / 4 / THREADS;

    for (int kt = 0; kt < K; kt += BK) {
        #pragma unroll
        for (int t = 0; t < A_LD4; ++t) {
            int idx = t * THREADS + tid;
            int row = idx / (BK / 4);
            int kq  = idx % (BK / 4);
            int gr  = r0 + row; if (gr >= M) gr = M - 1;
            float4 v = *(const float4*)&A[(size_t)gr * K + kt + kq * 4];
            As[kq * 4 + 0][row] = v.x;
            As[kq * 4 + 1][row] = v.y;
            As[kq * 4 + 2][row] = v.z;
            As[kq * 4 + 3][row] = v.w;
        }
        #pragma unroll
        for (int t = 0; t < W_LD4; ++t) {
            int idx = t * THREADS + tid;
            int kr = idx / (BN / 4);
            int nc = idx % (BN / 4);
            *(float4*)&Ws[kr][nc * 4] = *(const float4*)&W[(size_t)(kt + kr) * N + nc * 4];
        }
        __syncthreads();
        #pragma unroll
        for (int kk = 0; kk < BK; ++kk) {
            float a[TM], b[TN];
            #pragma unroll
            for (int m = 0; m < TM; m += 4) {
                float4 v = *(const float4*)&As[kk][trow * TM + m];
                a[m] = v.x; a[m+1] = v.y; a[m+2] = v.z; a[m+3] = v.w;
            }
            #pragma unroll
            for (int n = 0; n < TN; n += 4) {
                float4 v = *(const float4*)&Ws[kk][tcol * TN + n];
                b[n] = v.x; b[n+1] = v.y; b[n+2] = v.z; b[n+3] = v.w;
            }
            #pragma unroll
            for (int m = 0; m < TM; ++m)
                #pragma unroll
                for (int n = 0; n < TN; ++n)
                    acc[m][n] = fmaf(a[m], b[n], acc[m][n]);
        }
        __syncthreads();
    }
    #pragma unroll
    for (int m = 0; m < TM; ++m) {
        int gr = r0 + trow * TM + m;
        if (gr < M) {
            float4 v = { acc[m][0], acc[m][1], acc[m][2], acc[m][3] };
            *(float4*)&C[(size_t)gr * N + tcol * TN] = v;
        }
    }
}

// ---------------- fused gather-aggregate + self-loop + bias + BN + ReLU ----------------
// wave handles (node, 64-channel block); 4x edge unroll for MLP.
// out[i,c] = relu( BN( di * sum_s wnorm*t[s,c] + di^2*t[i,c] + bias[c] ) )

template<int NCB>
__global__ __launch_bounds__(256)
void gcn_gather(const float* __restrict__ t, float* __restrict__ out,
                const int* __restrict__ row_ptr, const int* __restrict__ col,
                const float* __restrict__ wnorm, const float* __restrict__ dinv,
                const float* __restrict__ bias,
                const float* __restrict__ gam, const float* __restrict__ bet,
                const float* __restrict__ mu,  const float* __restrict__ var,
                int Nn) {
    constexpr int C = NCB * 64;
    int wid  = (int)((blockIdx.x * 256 + threadIdx.x) >> 6);
    int lane = threadIdx.x & 63;
    int node = (NCB == 1) ? wid : (wid >> 1);
    int cb   = (NCB == 1) ? 0   : (wid & 1);
    if (node >= Nn) return;

    int b0 = row_ptr[node];
    int b1 = row_ptr[node + 1];
    float di = dinv[node];
    int c = cb * 64 + lane;

    float acc = 0.0f;
    int e = b0;
    for (; e + 4 <= b1; e += 4) {
        int   s0 = col[e],     s1 = col[e + 1],   s2 = col[e + 2],   s3 = col[e + 3];
        float w0 = wnorm[e],   w1 = wnorm[e + 1], w2 = wnorm[e + 2], w3 = wnorm[e + 3];
        float f0 = t[(size_t)s0 * C + c];
        float f1 = t[(size_t)s1 * C + c];
        float f2 = t[(size_t)s2 * C + c];
        float f3 = t[(size_t)s3 * C + c];
        acc = fmaf(w0, f0, acc);
        acc = fmaf(w1, f1, acc);
        acc = fmaf(w2, f2, acc);
        acc = fmaf(w3, f3, acc);
    }
    for (; e < b1; ++e) {
        int s = col[e];
        acc = fmaf(wnorm[e], t[(size_t)s * C + c], acc);
    }

    float d2 = di * di;
    float tv = t[(size_t)node * C + c];
    float sc = gam[c] * rsqrtf(var[c] + BN_EPS);
    float sh = bet[c] - mu[c] * sc;
    float h  = di * acc + d2 * tv + bias[c];
    out[(size_t)node * C + c] = fmaxf(h * sc + sh, 0.0f);
}

// ---------------- parallel pool: wave per 64-node chunk, lane = channel ----------------

__global__ __launch_bounds__(256)
void pool_sum_kernel(const float* __restrict__ h3, const int* __restrict__ batch,
                     float* __restrict__ sums, int Nn) {
    int wid  = (int)((blockIdx.x * 256 + threadIdx.x) >> 6);
    int lane = threadIdx.x & 63;
    int i0 = wid * 64;
    if (i0 >= Nn) return;
    int i1 = i0 + 64; if (i1 > Nn) i1 = Nn;

    float acc = 0.0f;
    int g = batch[i0];
    for (int i = i0; i < i1; ++i) {
        int gi = batch[i];
        if (gi != g) {
            unsafeAtomicAdd(&sums[g * 64 + lane], acc);
            acc = 0.0f;
            g = gi;
        }
        acc += h3[(size_t)i * 64 + lane];
    }
    unsafeAtomicAdd(&sums[g * 64 + lane], acc);
}

// ---------------- MLP head on pooled sums ----------------

__global__ __launch_bounds__(64)
void mlp_kernel(const float* __restrict__ sums, const int* __restrict__ start,
                const float* __restrict__ Wm1, const float* __restrict__ bm1,
                const float* __restrict__ Wm2, const float* __restrict__ bm2,
                float* __restrict__ out) {
    int g = blockIdx.x;
    int c = threadIdx.x;  // 64
    float cnt = (float)(start[g + 1] - start[g]);
    float pooled = sums[g * 64 + c] / fmaxf(cnt, 1.0f);
    __shared__ float pl[64];
    __shared__ float zl[64];
    pl[c] = pooled;
    __syncthreads();
    float z = bm1[c];
    for (int j = 0; j < 64; ++j) z = fmaf(pl[j], Wm1[j * 64 + c], z);
    z = fmaxf(z, 0.0f);
    zl[c] = z;
    __syncthreads();
    if (c < 10) {
        float o = bm2[c];
        for (int j = 0; j < 64; ++j) o = fmaf(zl[j], Wm2[j * 10 + c], o);
        out[g * 10 + c] = o;
    }
}

// ---------------- launcher ----------------

static inline int cdiv(int a, int b) { return (a + b - 1) / b; }

extern "C" void kernel_launch(void* const* d_in, const int* in_sizes, int n_in,
                              void* d_out, int out_size, void* d_ws, size_t ws_size,
                              hipStream_t stream) {
    const float* x   = (const float*)d_in[0];
    const int* edge  = (const int*)d_in[1];
    const int* batch = (const int*)d_in[2];
    const float* W1  = (const float*)d_in[3];
    const float* b1  = (const float*)d_in[4];
    const float* W2  = (const float*)d_in[5];
    const float* b2  = (const float*)d_in[6];
    const float* W3  = (const float*)d_in[7];
    const float* b3  = (const float*)d_in[8];
    const float* g1  = (const float*)d_in[9];
    const float* be1 = (const float*)d_in[10];
    const float* m1  = (const float*)d_in[11];
    const float* v1  = (const float*)d_in[12];
    const float* g2  = (const float*)d_in[13];
    const float* be2 = (const float*)d_in[14];
    const float* m2  = (const float*)d_in[15];
    const float* v2  = (const float*)d_in[16];
    const float* g3  = (const float*)d_in[17];
    const float* be3 = (const float*)d_in[18];
    const float* m3  = (const float*)d_in[19];
    const float* v3  = (const float*)d_in[20];
    const float* Wm1 = (const float*)d_in[21];
    const float* bm1 = (const float*)d_in[22];
    const float* Wm2 = (const float*)d_in[23];
    const float* bm2 = (const float*)d_in[24];
    float* outp = (float*)d_out;

    const int Nn = in_sizes[0] / 128;
    const int E  = in_sizes[1] / 2;
    const int G  = 128;
    const int* srcv = edge;
    const int* dstv = edge + E;

    // ws layout (floats): bufA(Nn*128) | bufB(Nn*128) | dinv(Nn) | row_ptr(Nn+1) | col(E) | wnorm(E) | start(G+1) | sums(G*64)
    float* ws      = (float*)d_ws;
    float* bufA    = ws;
    float* bufB    = bufA + (size_t)Nn * 128;
    float* dinv    = bufB + (size_t)Nn * 128;
    int*   row_ptr = (int*)(dinv + Nn);
    int*   col     = row_ptr + (Nn + 1);
    float* wnorm   = (float*)(col + E);
    int*   start   = (int*)(wnorm + E);
    float* sums    = (float*)(start + (G + 1));

    // transient ints overlaid on bufA (free until GEMM1 writes it)
    int* cnt  = (int*)bufA;            // Nn
    int* pos  = cnt + Nn;              // Nn
    int* bsum = pos + Nn;              // cdiv(Nn,256)

    const int TB = 256;
    const int nb = cdiv(Nn, 256);

    // ---- CSR build + norms + graph boundaries ----
    hipMemsetAsync(cnt, 0, (size_t)Nn * sizeof(int), stream);
    count_kernel<<<cdiv(E, TB), TB, 0, stream>>>(dstv, cnt, E);
    dinv_kernel<<<cdiv(Nn, TB), TB, 0, stream>>>(cnt, dinv, Nn);
    scan_block_kernel<<<nb, 256, 0, stream>>>(cnt, row_ptr, bsum, Nn);
    scan_sums_kernel<<<1, 512, 0, stream>>>(bsum, nb);
    add_offsets_kernel<<<nb, 256, 0, stream>>>(row_ptr, bsum, pos, Nn, E);
    scatter_kernel<<<cdiv(E, TB), TB, 0, stream>>>(srcv, dstv, dinv, pos, col, wnorm, E);
    boundary_kernel<<<cdiv(Nn, TB), TB, 0, stream>>>(batch, start, Nn, G);

    // ---- layer 1: t = x @ W1 (128->128); fused gather+BN+ReLU -> bufB ----
    gemm_f32<64, 128, 32, 8, 4, 128, 128><<<cdiv(Nn, 64), 256, 0, stream>>>(x, W1, bufA, Nn);
    gcn_gather<2><<<cdiv(Nn * 2, 4), 256, 0, stream>>>(bufA, bufB, row_ptr, col, wnorm, dinv,
                                                       b1, g1, be1, m1, v1, Nn);

    // ---- layer 2: t = h1 @ W2 (128->64) ----
    gemm_f32<128, 64, 32, 8, 4, 128, 64><<<cdiv(Nn, 128), 256, 0, stream>>>(bufB, W2, bufA, Nn);
    gcn_gather<1><<<cdiv(Nn, 4), 256, 0, stream>>>(bufA, bufB, row_ptr, col, wnorm, dinv,
                                                   b2, g2, be2, m2, v2, Nn);

    // ---- layer 3: t = h2 @ W3 (64->64) ----
    gemm_f32<128, 64, 32, 8, 4, 64, 64><<<cdiv(Nn, 128), 256, 0, stream>>>(bufB, W3, bufA, Nn);
    gcn_gather<1><<<cdiv(Nn, 4), 256, 0, stream>>>(bufA, bufB, row_ptr, col, wnorm, dinv,
                                                   b3, g3, be3, m3, v3, Nn);

    // ---- pool + MLP ----
    hipMemsetAsync(sums, 0, (size_t)G * 64 * sizeof(float), stream);
    pool_sum_kernel<<<cdiv(Nn, 256), 256, 0, stream>>>(bufB, batch, sums, Nn);
    mlp_kernel<<<G, 64, 0, stream>>>(sums, start, Wm1, bm1, Wm2, bm2, outp);
}

// Round 7
// 604.196 us; speedup vs baseline: 9.6633x; 1.0278x over previous
//
#include <hip/hip_runtime.h>
#include <math.h>

#define BN_EPS 1e-5f

// ---------------- CSR build: count / scan / scatter ----------------

__global__ void count_kernel(const int* __restrict__ dstv, int* __restrict__ cnt, int E) {
    int e = blockIdx.x * blockDim.x + threadIdx.x;
    if (e < E) atomicAdd(&cnt[dstv[e]], 1);
}

__global__ void dinv_kernel(const int* __restrict__ cnt, float* __restrict__ dinv, int n) {
    int i = blockIdx.x * blockDim.x + threadIdx.x;
    if (i < n) dinv[i] = rsqrtf((float)cnt[i] + 1.0f);  // +1 self-loop
}

// per-block exclusive scan; writes block-local exclusive + block total
__global__ void scan_block_kernel(const int* __restrict__ cnt, int* __restrict__ out,
                                  int* __restrict__ bsum, int Nn) {
    __shared__ int s[256];
    int t = threadIdx.x;
    int i = blockIdx.x * 256 + t;
    int v = (i < Nn) ? cnt[i] : 0;
    s[t] = v;
    __syncthreads();
    for (int off = 1; off < 256; off <<= 1) {
        int add = (t >= off) ? s[t - off] : 0;
        __syncthreads();
        s[t] += add;
        __syncthreads();
    }
    if (i < Nn) out[i] = s[t] - v;           // exclusive
    if (t == 255) bsum[blockIdx.x] = s[255]; // inclusive total
}

__global__ void scan_sums_kernel(int* __restrict__ bsum, int nb) {
    __shared__ int s[512];
    int t = threadIdx.x;
    int v = (t < nb) ? bsum[t] : 0;
    s[t] = v;
    __syncthreads();
    for (int off = 1; off < 512; off <<= 1) {
        int add = (t >= off) ? s[t - off] : 0;
        __syncthreads();
        s[t] += add;
        __syncthreads();
    }
    if (t < nb) bsum[t] = s[t] - v;          // exclusive
}

// adds block offsets AND initializes pos[] (merged copy_pos)
__global__ void add_offsets_kernel(int* __restrict__ row_ptr, const int* __restrict__ bsum,
                                   int* __restrict__ pos, int Nn, int E) {
    int i = blockIdx.x * 256 + threadIdx.x;
    if (i < Nn) {
        int v = row_ptr[i] + bsum[blockIdx.x];
        row_ptr[i] = v;
        pos[i] = v;
    }
    if (i == 0) row_ptr[Nn] = E;
}

// scatter edge -> CSR slot; also store wnorm[p] = dinv[src]
__global__ void scatter_kernel(const int* __restrict__ srcv, const int* __restrict__ dstv,
                               const float* __restrict__ dinv,
                               int* __restrict__ pos, int* __restrict__ col,
                               float* __restrict__ wnorm, int E) {
    int e = blockIdx.x * blockDim.x + threadIdx.x;
    if (e < E) {
        int s = srcv[e];
        int p = atomicAdd(&pos[dstv[e]], 1);
        col[p] = s;
        wnorm[p] = dinv[s];
    }
}

// batch is sorted; start[g] = first node of graph g, start[G] = N
__global__ void boundary_kernel(const int* __restrict__ batch, int* __restrict__ start,
                                int Nn, int G) {
    int i = blockIdx.x * blockDim.x + threadIdx.x;
    if (i >= Nn) return;
    int b = batch[i];
    if (i == 0) {
        for (int g = 0; g <= b; ++g) start[g] = 0;
    } else {
        int p = batch[i - 1];
        for (int g = p + 1; g <= b; ++g) start[g] = i;
    }
    if (i == Nn - 1) {
        for (int g = b + 1; g <= G; ++g) start[g] = Nn;
    }
}

// ---------------- f32 tiled GEMM: C[M,N] = A[M,K] @ W[K,N] ----------------
// 8x8 thread tile: 64 FMA per kk per thread.

template<int BM, int BN, int BK, int TM, int TN, int K, int N>
__global__ __launch_bounds__(256)
void gemm_f32(const float* __restrict__ A, const float* __restrict__ W,
              float* __restrict__ C, int M) {
    constexpr int THREADS = (BM / TM) * (BN / TN);
    static_assert(THREADS == 256, "bad tile config");
    __shared__ float As[BK][BM + 4];
    __shared__ float Ws[BK][BN];
    const int tid  = threadIdx.x;
    const int tcol = tid % (BN / TN);
    const int trow = tid / (BN / TN);
    const int r0   = blockIdx.x * BM;

    float acc[TM][TN] = {};

    constexpr int A_LD4 = BM * BK / 4 / THREADS;
    constexpr int W_LD4 = BK * BN / 4 / THREADS;

    for (int kt = 0; kt < K; kt += BK) {
        #pragma unroll
        for (int t = 0; t < A_LD4; ++t) {
            int idx = t * THREADS + tid;
            int row = idx / (BK / 4);
            int kq  = idx % (BK / 4);
            int gr  = r0 + row; if (gr >= M) gr = M - 1;
            float4 v = *(const float4*)&A[(size_t)gr * K + kt + kq * 4];
            As[kq * 4 + 0][row] = v.x;
            As[kq * 4 + 1][row] = v.y;
            As[kq * 4 + 2][row] = v.z;
            As[kq * 4 + 3][row] = v.w;
        }
        #pragma unroll
        for (int t = 0; t < W_LD4; ++t) {
            int idx = t * THREADS + tid;
            int kr = idx / (BN / 4);
            int nc = idx % (BN / 4);
            *(float4*)&Ws[kr][nc * 4] = *(const float4*)&W[(size_t)(kt + kr) * N + nc * 4];
        }
        __syncthreads();
        #pragma unroll
        for (int kk = 0; kk < BK; ++kk) {
            float a[TM], b[TN];
            #pragma unroll
            for (int m = 0; m < TM; m += 4) {
                float4 v = *(const float4*)&As[kk][trow * TM + m];
                a[m] = v.x; a[m+1] = v.y; a[m+2] = v.z; a[m+3] = v.w;
            }
            #pragma unroll
            for (int n = 0; n < TN; n += 4) {
                float4 v = *(const float4*)&Ws[kk][tcol * TN + n];
                b[n] = v.x; b[n+1] = v.y; b[n+2] = v.z; b[n+3] = v.w;
            }
            #pragma unroll
            for (int m = 0; m < TM; ++m)
                #pragma unroll
                for (int n = 0; n < TN; ++n)
                    acc[m][n] = fmaf(a[m], b[n], acc[m][n]);
        }
        __syncthreads();
    }
    #pragma unroll
    for (int m = 0; m < TM; ++m) {
        int gr = r0 + trow * TM + m;
        if (gr < M) {
            #pragma unroll
            for (int n = 0; n < TN; n += 4) {
                float4 v = { acc[m][n], acc[m][n+1], acc[m][n+2], acc[m][n+3] };
                *(float4*)&C[(size_t)gr * N + tcol * TN + n] = v;
            }
        }
    }
}

// ---------------- fused gather-aggregate + self-loop + bias + BN + ReLU ----------------
// wave handles (node, 64-channel block); 8x edge unroll for MLP (8 loads in flight).

template<int NCB>
__global__ __launch_bounds__(256)
void gcn_gather(const float* __restrict__ t, float* __restrict__ out,
                const int* __restrict__ row_ptr, const int* __restrict__ col,
                const float* __restrict__ wnorm, const float* __restrict__ dinv,
                const float* __restrict__ bias,
                const float* __restrict__ gam, const float* __restrict__ bet,
                const float* __restrict__ mu,  const float* __restrict__ var,
                int Nn) {
    constexpr int C = NCB * 64;
    int wid  = (int)((blockIdx.x * 256 + threadIdx.x) >> 6);
    int lane = threadIdx.x & 63;
    int node = (NCB == 1) ? wid : (wid >> 1);
    int cb   = (NCB == 1) ? 0   : (wid & 1);
    if (node >= Nn) return;

    int b0 = row_ptr[node];
    int b1 = row_ptr[node + 1];
    float di = dinv[node];
    int c = cb * 64 + lane;

    float acc = 0.0f;
    int e = b0;
    for (; e + 8 <= b1; e += 8) {
        int   s[8];
        float w[8];
        float f[8];
        #pragma unroll
        for (int u = 0; u < 8; ++u) { s[u] = col[e + u]; w[u] = wnorm[e + u]; }
        #pragma unroll
        for (int u = 0; u < 8; ++u) f[u] = t[(size_t)s[u] * C + c];
        #pragma unroll
        for (int u = 0; u < 8; ++u) acc = fmaf(w[u], f[u], acc);
    }
    for (; e + 4 <= b1; e += 4) {
        int   s0 = col[e],   s1 = col[e + 1],   s2 = col[e + 2],   s3 = col[e + 3];
        float w0 = wnorm[e], w1 = wnorm[e + 1], w2 = wnorm[e + 2], w3 = wnorm[e + 3];
        float f0 = t[(size_t)s0 * C + c];
        float f1 = t[(size_t)s1 * C + c];
        float f2 = t[(size_t)s2 * C + c];
        float f3 = t[(size_t)s3 * C + c];
        acc = fmaf(w0, f0, acc);
        acc = fmaf(w1, f1, acc);
        acc = fmaf(w2, f2, acc);
        acc = fmaf(w3, f3, acc);
    }
    for (; e < b1; ++e) {
        int s = col[e];
        acc = fmaf(wnorm[e], t[(size_t)s * C + c], acc);
    }

    float d2 = di * di;
    float tv = t[(size_t)node * C + c];
    float sc = gam[c] * rsqrtf(var[c] + BN_EPS);
    float sh = bet[c] - mu[c] * sc;
    float h  = di * acc + d2 * tv + bias[c];
    out[(size_t)node * C + c] = fmaxf(h * sc + sh, 0.0f);
}

// ---------------- parallel pool: wave per 64-node chunk, lane = channel ----------------

__global__ __launch_bounds__(256)
void pool_sum_kernel(const float* __restrict__ h3, const int* __restrict__ batch,
                     float* __restrict__ sums, int Nn) {
    int wid  = (int)((blockIdx.x * 256 + threadIdx.x) >> 6);
    int lane = threadIdx.x & 63;
    int i0 = wid * 64;
    if (i0 >= Nn) return;
    int i1 = i0 + 64; if (i1 > Nn) i1 = Nn;

    float acc = 0.0f;
    int g = batch[i0];
    for (int i = i0; i < i1; ++i) {
        int gi = batch[i];
        if (gi != g) {
            unsafeAtomicAdd(&sums[g * 64 + lane], acc);
            acc = 0.0f;
            g = gi;
        }
        acc += h3[(size_t)i * 64 + lane];
    }
    unsafeAtomicAdd(&sums[g * 64 + lane], acc);
}

// ---------------- MLP head on pooled sums ----------------

__global__ __launch_bounds__(64)
void mlp_kernel(const float* __restrict__ sums, const int* __restrict__ start,
                const float* __restrict__ Wm1, const float* __restrict__ bm1,
                const float* __restrict__ Wm2, const float* __restrict__ bm2,
                float* __restrict__ out) {
    int g = blockIdx.x;
    int c = threadIdx.x;  // 64
    float cnt = (float)(start[g + 1] - start[g]);
    float pooled = sums[g * 64 + c] / fmaxf(cnt, 1.0f);
    __shared__ float pl[64];
    __shared__ float zl[64];
    pl[c] = pooled;
    __syncthreads();
    float z = bm1[c];
    for (int j = 0; j < 64; ++j) z = fmaf(pl[j], Wm1[j * 64 + c], z);
    z = fmaxf(z, 0.0f);
    zl[c] = z;
    __syncthreads();
    if (c < 10) {
        float o = bm2[c];
        for (int j = 0; j < 64; ++j) o = fmaf(zl[j], Wm2[j * 10 + c], o);
        out[g * 10 + c] = o;
    }
}

// ---------------- launcher ----------------

static inline int cdiv(int a, int b) { return (a + b - 1) / b; }

extern "C" void kernel_launch(void* const* d_in, const int* in_sizes, int n_in,
                              void* d_out, int out_size, void* d_ws, size_t ws_size,
                              hipStream_t stream) {
    const float* x   = (const float*)d_in[0];
    const int* edge  = (const int*)d_in[1];
    const int* batch = (const int*)d_in[2];
    const float* W1  = (const float*)d_in[3];
    const float* b1  = (const float*)d_in[4];
    const float* W2  = (const float*)d_in[5];
    const float* b2  = (const float*)d_in[6];
    const float* W3  = (const float*)d_in[7];
    const float* b3  = (const float*)d_in[8];
    const float* g1  = (const float*)d_in[9];
    const float* be1 = (const float*)d_in[10];
    const float* m1  = (const float*)d_in[11];
    const float* v1  = (const float*)d_in[12];
    const float* g2  = (const float*)d_in[13];
    const float* be2 = (const float*)d_in[14];
    const float* m2  = (const float*)d_in[15];
    const float* v2  = (const float*)d_in[16];
    const float* g3  = (const float*)d_in[17];
    const float* be3 = (const float*)d_in[18];
    const float* m3  = (const float*)d_in[19];
    const float* v3  = (const float*)d_in[20];
    const float* Wm1 = (const float*)d_in[21];
    const float* bm1 = (const float*)d_in[22];
    const float* Wm2 = (const float*)d_in[23];
    const float* bm2 = (const float*)d_in[24];
    float* outp = (float*)d_out;

    const int Nn = in_sizes[0] / 128;
    const int E  = in_sizes[1] / 2;
    const int G  = 128;
    const int* srcv = edge;
    const int* dstv = edge + E;

    // ws layout (floats): bufA(Nn*128) | bufB(Nn*128) | dinv(Nn) | row_ptr(Nn+1) | col(E) | wnorm(E) | start(G+1) | sums(G*64)
    float* ws      = (float*)d_ws;
    float* bufA    = ws;
    float* bufB    = bufA + (size_t)Nn * 128;
    float* dinv    = bufB + (size_t)Nn * 128;
    int*   row_ptr = (int*)(dinv + Nn);
    int*   col     = row_ptr + (Nn + 1);
    float* wnorm   = (float*)(col + E);
    int*   start   = (int*)(wnorm + E);
    float* sums    = (float*)(start + (G + 1));

    // transient ints overlaid on bufA (free until GEMM1 writes it)
    int* cnt  = (int*)bufA;            // Nn
    int* pos  = cnt + Nn;              // Nn
    int* bsum = pos + Nn;              // cdiv(Nn,256)

    const int TB = 256;
    const int nb = cdiv(Nn, 256);

    // ---- CSR build + norms + graph boundaries ----
    hipMemsetAsync(cnt, 0, (size_t)Nn * sizeof(int), stream);
    count_kernel<<<cdiv(E, TB), TB, 0, stream>>>(dstv, cnt, E);
    dinv_kernel<<<cdiv(Nn, TB), TB, 0, stream>>>(cnt, dinv, Nn);
    scan_block_kernel<<<nb, 256, 0, stream>>>(cnt, row_ptr, bsum, Nn);
    scan_sums_kernel<<<1, 512, 0, stream>>>(bsum, nb);
    add_offsets_kernel<<<nb, 256, 0, stream>>>(row_ptr, bsum, pos, Nn, E);
    scatter_kernel<<<cdiv(E, TB), TB, 0, stream>>>(srcv, dstv, dinv, pos, col, wnorm, E);
    boundary_kernel<<<cdiv(Nn, TB), TB, 0, stream>>>(batch, start, Nn, G);

    // ---- layer 1: t = x @ W1 (128->128); fused gather+BN+ReLU -> bufB ----
    gemm_f32<128, 128, 32, 8, 8, 128, 128><<<cdiv(Nn, 128), 256, 0, stream>>>(x, W1, bufA, Nn);
    gcn_gather<2><<<cdiv(Nn * 2, 4), 256, 0, stream>>>(bufA, bufB, row_ptr, col, wnorm, dinv,
                                                       b1, g1, be1, m1, v1, Nn);

    // ---- layer 2: t = h1 @ W2 (128->64) ----
    gemm_f32<256, 64, 32, 8, 8, 128, 64><<<cdiv(Nn, 256), 256, 0, stream>>>(bufB, W2, bufA, Nn);
    gcn_gather<1><<<cdiv(Nn, 4), 256, 0, stream>>>(bufA, bufB, row_ptr, col, wnorm, dinv,
                                                   b2, g2, be2, m2, v2, Nn);

    // ---- layer 3: t = h2 @ W3 (64->64) ----
    gemm_f32<256, 64, 32, 8, 8, 64, 64><<<cdiv(Nn, 256), 256, 0, stream>>>(bufB, W3, bufA, Nn);
    gcn_gather<1><<<cdiv(Nn, 4), 256, 0, stream>>>(bufA, bufB, row_ptr, col, wnorm, dinv,
                                                   b3, g3, be3, m3, v3, Nn);

    // ---- pool + MLP ----
    hipMemsetAsync(sums, 0, (size_t)G * 64 * sizeof(float), stream);
    pool_sum_kernel<<<cdiv(Nn, 256), 256, 0, stream>>>(bufB, batch, sums, Nn);
    mlp_kernel<<<G, 64, 0, stream>>>(sums, start, Wm1, bm1, Wm2, bm2, outp);
}

// Round 8
// 535.465 us; speedup vs baseline: 10.9037x; 1.1284x over previous
//
#include <hip/hip_runtime.h>
#include <math.h>

#define BN_EPS 1e-5f

// ---------------- bf16 helpers (RNE) ----------------

__device__ __forceinline__ float bf2f(unsigned short u) {
    union { unsigned int i; float f; } v; v.i = ((unsigned int)u) << 16; return v.f;
}
__device__ __forceinline__ unsigned short f2bf(float f) {
    union { float f; unsigned int i; } v; v.f = f;
    unsigned int lsb = (v.i >> 16) & 1u;
    v.i += 0x7fffu + lsb;
    return (unsigned short)(v.i >> 16);
}
__device__ __forceinline__ unsigned int pack2bf(float a, float b) {
    return (unsigned int)f2bf(a) | ((unsigned int)f2bf(b) << 16);
}

// ---------------- CSR build: count / scan / scatter ----------------

__global__ void count_kernel(const int* __restrict__ dstv, int* __restrict__ cnt, int E) {
    int e = blockIdx.x * blockDim.x + threadIdx.x;
    if (e < E) atomicAdd(&cnt[dstv[e]], 1);
}

__global__ void dinv_kernel(const int* __restrict__ cnt, float* __restrict__ dinv, int n) {
    int i = blockIdx.x * blockDim.x + threadIdx.x;
    if (i < n) dinv[i] = rsqrtf((float)cnt[i] + 1.0f);  // +1 self-loop
}

__global__ void scan_block_kernel(const int* __restrict__ cnt, int* __restrict__ out,
                                  int* __restrict__ bsum, int Nn) {
    __shared__ int s[256];
    int t = threadIdx.x;
    int i = blockIdx.x * 256 + t;
    int v = (i < Nn) ? cnt[i] : 0;
    s[t] = v;
    __syncthreads();
    for (int off = 1; off < 256; off <<= 1) {
        int add = (t >= off) ? s[t - off] : 0;
        __syncthreads();
        s[t] += add;
        __syncthreads();
    }
    if (i < Nn) out[i] = s[t] - v;
    if (t == 255) bsum[blockIdx.x] = s[255];
}

__global__ void scan_sums_kernel(int* __restrict__ bsum, int nb) {
    __shared__ int s[512];
    int t = threadIdx.x;
    int v = (t < nb) ? bsum[t] : 0;
    s[t] = v;
    __syncthreads();
    for (int off = 1; off < 512; off <<= 1) {
        int add = (t >= off) ? s[t - off] : 0;
        __syncthreads();
        s[t] += add;
        __syncthreads();
    }
    if (t < nb) bsum[t] = s[t] - v;
}

__global__ void add_offsets_kernel(int* __restrict__ row_ptr, const int* __restrict__ bsum,
                                   int* __restrict__ pos, int Nn, int E) {
    int i = blockIdx.x * 256 + threadIdx.x;
    if (i < Nn) {
        int v = row_ptr[i] + bsum[blockIdx.x];
        row_ptr[i] = v;
        pos[i] = v;
    }
    if (i == 0) row_ptr[Nn] = E;
}

// scatter edge -> CSR slot; packed (col, wnorm) single 8B store
__global__ void scatter_kernel(const int* __restrict__ srcv, const int* __restrict__ dstv,
                               const float* __restrict__ dinv,
                               int* __restrict__ pos, int2* __restrict__ cw, int E) {
    int e = blockIdx.x * blockDim.x + threadIdx.x;
    if (e < E) {
        int s = srcv[e];
        float w = dinv[s];
        int p = atomicAdd(&pos[dstv[e]], 1);
        cw[p] = make_int2(s, __float_as_int(w));
    }
}

__global__ void boundary_kernel(const int* __restrict__ batch, int* __restrict__ start,
                                int Nn, int G) {
    int i = blockIdx.x * blockDim.x + threadIdx.x;
    if (i >= Nn) return;
    int b = batch[i];
    if (i == 0) {
        for (int g = 0; g <= b; ++g) start[g] = 0;
    } else {
        int p = batch[i - 1];
        for (int g = p + 1; g <= b; ++g) start[g] = i;
    }
    if (i == Nn - 1) {
        for (int g = b + 1; g <= G; ++g) start[g] = Nn;
    }
}

// ---------------- tiled GEMM: C[M,N](bf16) = A[M,K](f32|bf16) @ W[K,N](f32) ----------------

template<int BM, int BN, int BK, int TM, int TN, int K, int N, bool ABF16>
__global__ __launch_bounds__(256)
void gemm_k(const void* __restrict__ Ap, const float* __restrict__ W,
            unsigned short* __restrict__ C, int M) {
    constexpr int THREADS = (BM / TM) * (BN / TN);
    static_assert(THREADS == 256, "bad tile config");
    __shared__ float As[BK][BM + 4];
    __shared__ float Ws[BK][BN];
    const int tid  = threadIdx.x;
    const int tcol = tid % (BN / TN);
    const int trow = tid / (BN / TN);
    const int r0   = blockIdx.x * BM;

    float acc[TM][TN] = {};

    for (int kt = 0; kt < K; kt += BK) {
        if constexpr (ABF16) {
            const unsigned short* A = (const unsigned short*)Ap;
            constexpr int NCH = BM * BK / 8 / THREADS;   // 8 bf16 per chunk
            #pragma unroll
            for (int t = 0; t < NCH; ++t) {
                int idx = t * THREADS + tid;             // [0, BM*BK/8)
                int row = idx / (BK / 8);
                int k0  = (idx % (BK / 8)) * 8;
                int gr  = r0 + row; if (gr >= M) gr = M - 1;
                uint4 u = *(const uint4*)&A[(size_t)gr * K + kt + k0];
                As[k0 + 0][row] = bf2f((unsigned short)(u.x & 0xffff));
                As[k0 + 1][row] = bf2f((unsigned short)(u.x >> 16));
                As[k0 + 2][row] = bf2f((unsigned short)(u.y & 0xffff));
                As[k0 + 3][row] = bf2f((unsigned short)(u.y >> 16));
                As[k0 + 4][row] = bf2f((unsigned short)(u.z & 0xffff));
                As[k0 + 5][row] = bf2f((unsigned short)(u.z >> 16));
                As[k0 + 6][row] = bf2f((unsigned short)(u.w & 0xffff));
                As[k0 + 7][row] = bf2f((unsigned short)(u.w >> 16));
            }
        } else {
            const float* A = (const float*)Ap;
            constexpr int NCH = BM * BK / 4 / THREADS;
            #pragma unroll
            for (int t = 0; t < NCH; ++t) {
                int idx = t * THREADS + tid;
                int row = idx / (BK / 4);
                int kq  = idx % (BK / 4);
                int gr  = r0 + row; if (gr >= M) gr = M - 1;
                float4 v = *(const float4*)&A[(size_t)gr * K + kt + kq * 4];
                As[kq * 4 + 0][row] = v.x;
                As[kq * 4 + 1][row] = v.y;
                As[kq * 4 + 2][row] = v.z;
                As[kq * 4 + 3][row] = v.w;
            }
        }
        constexpr int W_LD4 = BK * BN / 4 / THREADS;
        #pragma unroll
        for (int t = 0; t < W_LD4; ++t) {
            int idx = t * THREADS + tid;
            int kr = idx / (BN / 4);
            int nc = idx % (BN / 4);
            *(float4*)&Ws[kr][nc * 4] = *(const float4*)&W[(size_t)(kt + kr) * N + nc * 4];
        }
        __syncthreads();
        #pragma unroll
        for (int kk = 0; kk < BK; ++kk) {
            float a[TM], b[TN];
            #pragma unroll
            for (int m = 0; m < TM; m += 4) {
                float4 v = *(const float4*)&As[kk][trow * TM + m];
                a[m] = v.x; a[m+1] = v.y; a[m+2] = v.z; a[m+3] = v.w;
            }
            #pragma unroll
            for (int n = 0; n < TN; n += 4) {
                float4 v = *(const float4*)&Ws[kk][tcol * TN + n];
                b[n] = v.x; b[n+1] = v.y; b[n+2] = v.z; b[n+3] = v.w;
            }
            #pragma unroll
            for (int m = 0; m < TM; ++m)
                #pragma unroll
                for (int n = 0; n < TN; ++n)
                    acc[m][n] = fmaf(a[m], b[n], acc[m][n]);
        }
        __syncthreads();
    }
    #pragma unroll
    for (int m = 0; m < TM; ++m) {
        int gr = r0 + trow * TM + m;
        if (gr < M) {
            #pragma unroll
            for (int n = 0; n < TN; n += 4) {
                uint2 p;
                p.x = pack2bf(acc[m][n + 0], acc[m][n + 1]);
                p.y = pack2bf(acc[m][n + 2], acc[m][n + 3]);
                *(uint2*)&C[(size_t)gr * N + tcol * TN + n] = p;
            }
        }
    }
}

// ---------------- fused gather + self-loop + bias + BN + ReLU (bf16 in/out) ----------------
// C=128: one wave per node, lane handles channels {2*lane, 2*lane+1} via uint loads.

__global__ __launch_bounds__(256)
void gcn_gather128(const unsigned short* __restrict__ t, unsigned short* __restrict__ out,
                   const int* __restrict__ row_ptr, const int2* __restrict__ cw,
                   const float* __restrict__ dinv,
                   const float* __restrict__ bias,
                   const float* __restrict__ gam, const float* __restrict__ bet,
                   const float* __restrict__ mu,  const float* __restrict__ var,
                   int Nn) {
    int node = (int)((blockIdx.x * 256 + threadIdx.x) >> 6);
    int lane = threadIdx.x & 63;
    if (node >= Nn) return;

    int b0 = row_ptr[node];
    int b1 = row_ptr[node + 1];
    float di = dinv[node];
    const unsigned int* tu = (const unsigned int*)t;

    float acc0 = 0.0f, acc1 = 0.0f;
    int e = b0;
    for (; e + 8 <= b1; e += 8) {
        int2 c8[8];
        unsigned int f[8];
        #pragma unroll
        for (int u = 0; u < 8; ++u) c8[u] = cw[e + u];
        #pragma unroll
        for (int u = 0; u < 8; ++u) f[u] = tu[(size_t)c8[u].x * 64 + lane];
        #pragma unroll
        for (int u = 0; u < 8; ++u) {
            float w = __int_as_float(c8[u].y);
            acc0 = fmaf(w, bf2f((unsigned short)(f[u] & 0xffff)), acc0);
            acc1 = fmaf(w, bf2f((unsigned short)(f[u] >> 16)),   acc1);
        }
    }
    for (; e < b1; ++e) {
        int2 c = cw[e];
        unsigned int f = tu[(size_t)c.x * 64 + lane];
        float w = __int_as_float(c.y);
        acc0 = fmaf(w, bf2f((unsigned short)(f & 0xffff)), acc0);
        acc1 = fmaf(w, bf2f((unsigned short)(f >> 16)),   acc1);
    }

    float d2 = di * di;
    unsigned int tv = tu[(size_t)node * 64 + lane];
    int c0 = 2 * lane, c1 = 2 * lane + 1;
    float sc0 = gam[c0] * rsqrtf(var[c0] + BN_EPS);
    float sc1 = gam[c1] * rsqrtf(var[c1] + BN_EPS);
    float sh0 = bet[c0] - mu[c0] * sc0;
    float sh1 = bet[c1] - mu[c1] * sc1;
    float h0 = di * acc0 + d2 * bf2f((unsigned short)(tv & 0xffff)) + bias[c0];
    float h1 = di * acc1 + d2 * bf2f((unsigned short)(tv >> 16))   + bias[c1];
    float o0 = fmaxf(h0 * sc0 + sh0, 0.0f);
    float o1 = fmaxf(h1 * sc1 + sh1, 0.0f);
    ((unsigned int*)out)[(size_t)node * 64 + lane] = pack2bf(o0, o1);
}

// C=64: one wave per node, lane = channel (ushort loads).

__global__ __launch_bounds__(256)
void gcn_gather64(const unsigned short* __restrict__ t, unsigned short* __restrict__ out,
                  const int* __restrict__ row_ptr, const int2* __restrict__ cw,
                  const float* __restrict__ dinv,
                  const float* __restrict__ bias,
                  const float* __restrict__ gam, const float* __restrict__ bet,
                  const float* __restrict__ mu,  const float* __restrict__ var,
                  int Nn) {
    int node = (int)((blockIdx.x * 256 + threadIdx.x) >> 6);
    int lane = threadIdx.x & 63;
    if (node >= Nn) return;

    int b0 = row_ptr[node];
    int b1 = row_ptr[node + 1];
    float di = dinv[node];

    float acc = 0.0f;
    int e = b0;
    for (; e + 8 <= b1; e += 8) {
        int2 c8[8];
        unsigned short f[8];
        #pragma unroll
        for (int u = 0; u < 8; ++u) c8[u] = cw[e + u];
        #pragma unroll
        for (int u = 0; u < 8; ++u) f[u] = t[(size_t)c8[u].x * 64 + lane];
        #pragma unroll
        for (int u = 0; u < 8; ++u)
            acc = fmaf(__int_as_float(c8[u].y), bf2f(f[u]), acc);
    }
    for (; e < b1; ++e) {
        int2 c = cw[e];
        acc = fmaf(__int_as_float(c.y), bf2f(t[(size_t)c.x * 64 + lane]), acc);
    }

    float d2 = di * di;
    float tv = bf2f(t[(size_t)node * 64 + lane]);
    int c = lane;
    float sc = gam[c] * rsqrtf(var[c] + BN_EPS);
    float sh = bet[c] - mu[c] * sc;
    float h  = di * acc + d2 * tv + bias[c];
    out[(size_t)node * 64 + lane] = f2bf(fmaxf(h * sc + sh, 0.0f));
}

// ---------------- parallel pool: wave per 64-node chunk, lane = channel ----------------

__global__ __launch_bounds__(256)
void pool_sum_kernel(const unsigned short* __restrict__ h3, const int* __restrict__ batch,
                     float* __restrict__ sums, int Nn) {
    int wid  = (int)((blockIdx.x * 256 + threadIdx.x) >> 6);
    int lane = threadIdx.x & 63;
    int i0 = wid * 64;
    if (i0 >= Nn) return;
    int i1 = i0 + 64; if (i1 > Nn) i1 = Nn;

    float acc = 0.0f;
    int g = batch[i0];
    for (int i = i0; i < i1; ++i) {
        int gi = batch[i];
        if (gi != g) {
            unsafeAtomicAdd(&sums[g * 64 + lane], acc);
            acc = 0.0f;
            g = gi;
        }
        acc += bf2f(h3[(size_t)i * 64 + lane]);
    }
    unsafeAtomicAdd(&sums[g * 64 + lane], acc);
}

// ---------------- MLP head on pooled sums ----------------

__global__ __launch_bounds__(64)
void mlp_kernel(const float* __restrict__ sums, const int* __restrict__ start,
                const float* __restrict__ Wm1, const float* __restrict__ bm1,
                const float* __restrict__ Wm2, const float* __restrict__ bm2,
                float* __restrict__ out) {
    int g = blockIdx.x;
    int c = threadIdx.x;  // 64
    float cnt = (float)(start[g + 1] - start[g]);
    float pooled = sums[g * 64 + c] / fmaxf(cnt, 1.0f);
    __shared__ float pl[64];
    __shared__ float zl[64];
    pl[c] = pooled;
    __syncthreads();
    float z = bm1[c];
    for (int j = 0; j < 64; ++j) z = fmaf(pl[j], Wm1[j * 64 + c], z);
    z = fmaxf(z, 0.0f);
    zl[c] = z;
    __syncthreads();
    if (c < 10) {
        float o = bm2[c];
        for (int j = 0; j < 64; ++j) o = fmaf(zl[j], Wm2[j * 10 + c], o);
        out[g * 10 + c] = o;
    }
}

// ---------------- launcher ----------------

static inline int cdiv(int a, int b) { return (a + b - 1) / b; }

extern "C" void kernel_launch(void* const* d_in, const int* in_sizes, int n_in,
                              void* d_out, int out_size, void* d_ws, size_t ws_size,
                              hipStream_t stream) {
    const float* x   = (const float*)d_in[0];
    const int* edge  = (const int*)d_in[1];
    const int* batch = (const int*)d_in[2];
    const float* W1  = (const float*)d_in[3];
    const float* b1  = (const float*)d_in[4];
    const float* W2  = (const float*)d_in[5];
    const float* b2  = (const float*)d_in[6];
    const float* W3  = (const float*)d_in[7];
    const float* b3  = (const float*)d_in[8];
    const float* g1  = (const float*)d_in[9];
    const float* be1 = (const float*)d_in[10];
    const float* m1  = (const float*)d_in[11];
    const float* v1  = (const float*)d_in[12];
    const float* g2  = (const float*)d_in[13];
    const float* be2 = (const float*)d_in[14];
    const float* m2  = (const float*)d_in[15];
    const float* v2  = (const float*)d_in[16];
    const float* g3  = (const float*)d_in[17];
    const float* be3 = (const float*)d_in[18];
    const float* m3  = (const float*)d_in[19];
    const float* v3  = (const float*)d_in[20];
    const float* Wm1 = (const float*)d_in[21];
    const float* bm1 = (const float*)d_in[22];
    const float* Wm2 = (const float*)d_in[23];
    const float* bm2 = (const float*)d_in[24];
    float* outp = (float*)d_out;

    const int Nn = in_sizes[0] / 128;
    const int E  = in_sizes[1] / 2;
    const int G  = 128;
    const int* srcv = edge;
    const int* dstv = edge + E;

    // ws layout (bytes):
    // bufA (Nn*128 bf16) | bufB (Nn*128 bf16) | dinv (Nn f32) | cw (E int2)
    // | row_ptr (Nn+1 int) | start (G+1 int) | sums (G*64 f32)
    char* wsb = (char*)d_ws;
    unsigned short* bufA = (unsigned short*)wsb;
    unsigned short* bufB = bufA + (size_t)Nn * 128;
    float* dinv    = (float*)(bufB + (size_t)Nn * 128);
    int2*  cw      = (int2*)(dinv + Nn);
    int*   row_ptr = (int*)(cw + E);
    int*   start   = row_ptr + (Nn + 1);
    float* sums    = (float*)(start + (G + 1));

    // transient ints overlaid on bufA (free until GEMM1 writes it)
    int* cnt  = (int*)bufA;            // Nn
    int* pos  = cnt + Nn;              // Nn
    int* bsum = pos + Nn;              // cdiv(Nn,256)

    const int TB = 256;
    const int nb = cdiv(Nn, 256);

    // ---- CSR build + norms + graph boundaries ----
    hipMemsetAsync(cnt, 0, (size_t)Nn * sizeof(int), stream);
    count_kernel<<<cdiv(E, TB), TB, 0, stream>>>(dstv, cnt, E);
    dinv_kernel<<<cdiv(Nn, TB), TB, 0, stream>>>(cnt, dinv, Nn);
    scan_block_kernel<<<nb, 256, 0, stream>>>(cnt, row_ptr, bsum, Nn);
    scan_sums_kernel<<<1, 512, 0, stream>>>(bsum, nb);
    add_offsets_kernel<<<nb, 256, 0, stream>>>(row_ptr, bsum, pos, Nn, E);
    scatter_kernel<<<cdiv(E, TB), TB, 0, stream>>>(srcv, dstv, dinv, pos, cw, E);
    boundary_kernel<<<cdiv(Nn, TB), TB, 0, stream>>>(batch, start, Nn, G);

    // ---- layer 1: t = x @ W1 (128->128, f32 in, bf16 out); gather -> bufB ----
    gemm_k<128, 128, 32, 8, 8, 128, 128, false><<<cdiv(Nn, 128), 256, 0, stream>>>(x, W1, bufA, Nn);
    gcn_gather128<<<cdiv(Nn, 4), 256, 0, stream>>>(bufA, bufB, row_ptr, cw, dinv,
                                                   b1, g1, be1, m1, v1, Nn);

    // ---- layer 2: t = h1 @ W2 (128->64, bf16 in/out) ----
    gemm_k<256, 64, 32, 8, 8, 128, 64, true><<<cdiv(Nn, 256), 256, 0, stream>>>(bufB, W2, bufA, Nn);
    gcn_gather64<<<cdiv(Nn, 4), 256, 0, stream>>>(bufA, bufB, row_ptr, cw, dinv,
                                                  b2, g2, be2, m2, v2, Nn);

    // ---- layer 3: t = h2 @ W3 (64->64, bf16 in/out) ----
    gemm_k<256, 64, 32, 8, 8, 64, 64, true><<<cdiv(Nn, 256), 256, 0, stream>>>(bufB, W3, bufA, Nn);
    gcn_gather64<<<cdiv(Nn, 4), 256, 0, stream>>>(bufA, bufB, row_ptr, cw, dinv,
                                                  b3, g3, be3, m3, v3, Nn);

    // ---- pool + MLP ----
    hipMemsetAsync(sums, 0, (size_t)G * 64 * sizeof(float), stream);
    pool_sum_kernel<<<cdiv(Nn, 256), 256, 0, stream>>>(bufB, batch, sums, Nn);
    mlp_kernel<<<G, 64, 0, stream>>>(sums, start, Wm1, bm1, Wm2, bm2, outp);
}

// Round 9
// 518.039 us; speedup vs baseline: 11.2705x; 1.0336x over previous
//
#include <hip/hip_runtime.h>
#include <math.h>

#define BN_EPS 1e-5f

// ---------------- bf16 helpers (RNE) ----------------

__device__ __forceinline__ float bf2f(unsigned short u) {
    union { unsigned int i; float f; } v; v.i = ((unsigned int)u) << 16; return v.f;
}
__device__ __forceinline__ unsigned short f2bf(float f) {
    union { float f; unsigned int i; } v; v.f = f;
    unsigned int lsb = (v.i >> 16) & 1u;
    v.i += 0x7fffu + lsb;
    return (unsigned short)(v.i >> 16);
}
__device__ __forceinline__ unsigned int pack2bf(float a, float b) {
    return (unsigned int)f2bf(a) | ((unsigned int)f2bf(b) << 16);
}

// ---------------- CSR build: count / scan / scatter ----------------

__global__ void count_kernel(const int* __restrict__ dstv, int* __restrict__ cnt, int E) {
    int e = blockIdx.x * blockDim.x + threadIdx.x;
    if (e < E) atomicAdd(&cnt[dstv[e]], 1);
}

__global__ void dinv_kernel(const int* __restrict__ cnt, float* __restrict__ dinv, int n) {
    int i = blockIdx.x * blockDim.x + threadIdx.x;
    if (i < n) dinv[i] = rsqrtf((float)cnt[i] + 1.0f);  // +1 self-loop
}

__global__ void scan_block_kernel(const int* __restrict__ cnt, int* __restrict__ out,
                                  int* __restrict__ bsum, int Nn) {
    __shared__ int s[256];
    int t = threadIdx.x;
    int i = blockIdx.x * 256 + t;
    int v = (i < Nn) ? cnt[i] : 0;
    s[t] = v;
    __syncthreads();
    for (int off = 1; off < 256; off <<= 1) {
        int add = (t >= off) ? s[t - off] : 0;
        __syncthreads();
        s[t] += add;
        __syncthreads();
    }
    if (i < Nn) out[i] = s[t] - v;
    if (t == 255) bsum[blockIdx.x] = s[255];
}

__global__ void scan_sums_kernel(int* __restrict__ bsum, int nb) {
    __shared__ int s[512];
    int t = threadIdx.x;
    int v = (t < nb) ? bsum[t] : 0;
    s[t] = v;
    __syncthreads();
    for (int off = 1; off < 512; off <<= 1) {
        int add = (t >= off) ? s[t - off] : 0;
        __syncthreads();
        s[t] += add;
        __syncthreads();
    }
    if (t < nb) bsum[t] = s[t] - v;
}

__global__ void add_offsets_kernel(int* __restrict__ row_ptr, const int* __restrict__ bsum,
                                   int* __restrict__ pos, int Nn, int E) {
    int i = blockIdx.x * 256 + threadIdx.x;
    if (i < Nn) {
        int v = row_ptr[i] + bsum[blockIdx.x];
        row_ptr[i] = v;
        pos[i] = v;
    }
    if (i == 0) row_ptr[Nn] = E;
}

// dst-partitioned scatter: part = blockIdx&7 -> one XCD per dst-range, so each
// cw cache line is only dirtied in a single L2 (kills the 8x write amplification).
__global__ __launch_bounds__(256)
void scatter_kernel(const int* __restrict__ srcv, const int* __restrict__ dstv,
                    const float* __restrict__ dinv,
                    int* __restrict__ pos, int2* __restrict__ cw, int E, int Nn) {
    int part    = blockIdx.x & 7;
    int chunk   = blockIdx.x >> 3;
    int nchunks = gridDim.x >> 3;
    int lo = (int)((long long)part * Nn >> 3);
    int hi = (part == 7) ? Nn : (int)((long long)(part + 1) * Nn >> 3);
    for (int e = chunk * 256 + threadIdx.x; e < E; e += nchunks * 256) {
        int d = dstv[e];
        if (d >= lo && d < hi) {
            int s = srcv[e];
            float w = dinv[s];
            int p = atomicAdd(&pos[d], 1);
            cw[p] = make_int2(s, __float_as_int(w));
        }
    }
}

__global__ void boundary_kernel(const int* __restrict__ batch, int* __restrict__ start,
                                int Nn, int G) {
    int i = blockIdx.x * blockDim.x + threadIdx.x;
    if (i >= Nn) return;
    int b = batch[i];
    if (i == 0) {
        for (int g = 0; g <= b; ++g) start[g] = 0;
    } else {
        int p = batch[i - 1];
        for (int g = p + 1; g <= b; ++g) start[g] = i;
    }
    if (i == Nn - 1) {
        for (int g = b + 1; g <= G; ++g) start[g] = Nn;
    }
}

// ---------------- tiled GEMM: C[M,N](bf16) = A[M,K](f32|bf16) @ W[K,N](f32) ----------------

template<int BM, int BN, int BK, int TM, int TN, int K, int N, bool ABF16>
__global__ __launch_bounds__(256)
void gemm_k(const void* __restrict__ Ap, const float* __restrict__ W,
            unsigned short* __restrict__ C, int M) {
    constexpr int THREADS = (BM / TM) * (BN / TN);
    static_assert(THREADS == 256, "bad tile config");
    __shared__ float As[BK][BM + 4];
    __shared__ float Ws[BK][BN];
    const int tid  = threadIdx.x;
    const int tcol = tid % (BN / TN);
    const int trow = tid / (BN / TN);
    const int r0   = blockIdx.x * BM;

    float acc[TM][TN] = {};

    for (int kt = 0; kt < K; kt += BK) {
        if constexpr (ABF16) {
            const unsigned short* A = (const unsigned short*)Ap;
            constexpr int NCH = BM * BK / 8 / THREADS;   // 8 bf16 per chunk
            #pragma unroll
            for (int t = 0; t < NCH; ++t) {
                int idx = t * THREADS + tid;             // [0, BM*BK/8)
                int row = idx / (BK / 8);
                int k0  = (idx % (BK / 8)) * 8;
                int gr  = r0 + row; if (gr >= M) gr = M - 1;
                uint4 u = *(const uint4*)&A[(size_t)gr * K + kt + k0];
                As[k0 + 0][row] = bf2f((unsigned short)(u.x & 0xffff));
                As[k0 + 1][row] = bf2f((unsigned short)(u.x >> 16));
                As[k0 + 2][row] = bf2f((unsigned short)(u.y & 0xffff));
                As[k0 + 3][row] = bf2f((unsigned short)(u.y >> 16));
                As[k0 + 4][row] = bf2f((unsigned short)(u.z & 0xffff));
                As[k0 + 5][row] = bf2f((unsigned short)(u.z >> 16));
                As[k0 + 6][row] = bf2f((unsigned short)(u.w & 0xffff));
                As[k0 + 7][row] = bf2f((unsigned short)(u.w >> 16));
            }
        } else {
            const float* A = (const float*)Ap;
            constexpr int NCH = BM * BK / 4 / THREADS;
            #pragma unroll
            for (int t = 0; t < NCH; ++t) {
                int idx = t * THREADS + tid;
                int row = idx / (BK / 4);
                int kq  = idx % (BK / 4);
                int gr  = r0 + row; if (gr >= M) gr = M - 1;
                float4 v = *(const float4*)&A[(size_t)gr * K + kt + kq * 4];
                As[kq * 4 + 0][row] = v.x;
                As[kq * 4 + 1][row] = v.y;
                As[kq * 4 + 2][row] = v.z;
                As[kq * 4 + 3][row] = v.w;
            }
        }
        constexpr int W_LD4 = BK * BN / 4 / THREADS;
        #pragma unroll
        for (int t = 0; t < W_LD4; ++t) {
            int idx = t * THREADS + tid;
            int kr = idx / (BN / 4);
            int nc = idx % (BN / 4);
            *(float4*)&Ws[kr][nc * 4] = *(const float4*)&W[(size_t)(kt + kr) * N + nc * 4];
        }
        __syncthreads();
        #pragma unroll
        for (int kk = 0; kk < BK; ++kk) {
            float a[TM], b[TN];
            #pragma unroll
            for (int m = 0; m < TM; m += 4) {
                float4 v = *(const float4*)&As[kk][trow * TM + m];
                a[m] = v.x; a[m+1] = v.y; a[m+2] = v.z; a[m+3] = v.w;
            }
            #pragma unroll
            for (int n = 0; n < TN; n += 4) {
                float4 v = *(const float4*)&Ws[kk][tcol * TN + n];
                b[n] = v.x; b[n+1] = v.y; b[n+2] = v.z; b[n+3] = v.w;
            }
            #pragma unroll
            for (int m = 0; m < TM; ++m)
                #pragma unroll
                for (int n = 0; n < TN; ++n)
                    acc[m][n] = fmaf(a[m], b[n], acc[m][n]);
        }
        __syncthreads();
    }
    #pragma unroll
    for (int m = 0; m < TM; ++m) {
        int gr = r0 + trow * TM + m;
        if (gr < M) {
            #pragma unroll
            for (int n = 0; n < TN; n += 4) {
                uint2 p;
                p.x = pack2bf(acc[m][n + 0], acc[m][n + 1]);
                p.y = pack2bf(acc[m][n + 2], acc[m][n + 3]);
                *(uint2*)&C[(size_t)gr * N + tcol * TN + n] = p;
            }
        }
    }
}

// ---------------- fused gather + self-loop + bias + BN + ReLU (bf16 in/out) ----------------

__global__ __launch_bounds__(256)
void gcn_gather128(const unsigned short* __restrict__ t, unsigned short* __restrict__ out,
                   const int* __restrict__ row_ptr, const int2* __restrict__ cw,
                   const float* __restrict__ dinv,
                   const float* __restrict__ bias,
                   const float* __restrict__ gam, const float* __restrict__ bet,
                   const float* __restrict__ mu,  const float* __restrict__ var,
                   int Nn) {
    int node = (int)((blockIdx.x * 256 + threadIdx.x) >> 6);
    int lane = threadIdx.x & 63;
    if (node >= Nn) return;

    int b0 = row_ptr[node];
    int b1 = row_ptr[node + 1];
    float di = dinv[node];
    const unsigned int* tu = (const unsigned int*)t;

    float acc0 = 0.0f, acc1 = 0.0f;
    int e = b0;
    for (; e + 8 <= b1; e += 8) {
        int2 c8[8];
        unsigned int f[8];
        #pragma unroll
        for (int u = 0; u < 8; ++u) c8[u] = cw[e + u];
        #pragma unroll
        for (int u = 0; u < 8; ++u) f[u] = tu[(size_t)c8[u].x * 64 + lane];
        #pragma unroll
        for (int u = 0; u < 8; ++u) {
            float w = __int_as_float(c8[u].y);
            acc0 = fmaf(w, bf2f((unsigned short)(f[u] & 0xffff)), acc0);
            acc1 = fmaf(w, bf2f((unsigned short)(f[u] >> 16)),   acc1);
        }
    }
    for (; e < b1; ++e) {
        int2 c = cw[e];
        unsigned int f = tu[(size_t)c.x * 64 + lane];
        float w = __int_as_float(c.y);
        acc0 = fmaf(w, bf2f((unsigned short)(f & 0xffff)), acc0);
        acc1 = fmaf(w, bf2f((unsigned short)(f >> 16)),   acc1);
    }

    float d2 = di * di;
    unsigned int tv = tu[(size_t)node * 64 + lane];
    int c0 = 2 * lane, c1 = 2 * lane + 1;
    float sc0 = gam[c0] * rsqrtf(var[c0] + BN_EPS);
    float sc1 = gam[c1] * rsqrtf(var[c1] + BN_EPS);
    float sh0 = bet[c0] - mu[c0] * sc0;
    float sh1 = bet[c1] - mu[c1] * sc1;
    float h0 = di * acc0 + d2 * bf2f((unsigned short)(tv & 0xffff)) + bias[c0];
    float h1 = di * acc1 + d2 * bf2f((unsigned short)(tv >> 16))   + bias[c1];
    float o0 = fmaxf(h0 * sc0 + sh0, 0.0f);
    float o1 = fmaxf(h1 * sc1 + sh1, 0.0f);
    ((unsigned int*)out)[(size_t)node * 64 + lane] = pack2bf(o0, o1);
}

__global__ __launch_bounds__(256)
void gcn_gather64(const unsigned short* __restrict__ t, unsigned short* __restrict__ out,
                  const int* __restrict__ row_ptr, const int2* __restrict__ cw,
                  const float* __restrict__ dinv,
                  const float* __restrict__ bias,
                  const float* __restrict__ gam, const float* __restrict__ bet,
                  const float* __restrict__ mu,  const float* __restrict__ var,
                  int Nn) {
    int node = (int)((blockIdx.x * 256 + threadIdx.x) >> 6);
    int lane = threadIdx.x & 63;
    if (node >= Nn) return;

    int b0 = row_ptr[node];
    int b1 = row_ptr[node + 1];
    float di = dinv[node];

    float acc = 0.0f;
    int e = b0;
    for (; e + 8 <= b1; e += 8) {
        int2 c8[8];
        unsigned short f[8];
        #pragma unroll
        for (int u = 0; u < 8; ++u) c8[u] = cw[e + u];
        #pragma unroll
        for (int u = 0; u < 8; ++u) f[u] = t[(size_t)c8[u].x * 64 + lane];
        #pragma unroll
        for (int u = 0; u < 8; ++u)
            acc = fmaf(__int_as_float(c8[u].y), bf2f(f[u]), acc);
    }
    for (; e < b1; ++e) {
        int2 c = cw[e];
        acc = fmaf(__int_as_float(c.y), bf2f(t[(size_t)c.x * 64 + lane]), acc);
    }

    float d2 = di * di;
    float tv = bf2f(t[(size_t)node * 64 + lane]);
    int c = lane;
    float sc = gam[c] * rsqrtf(var[c] + BN_EPS);
    float sh = bet[c] - mu[c] * sc;
    float h  = di * acc + d2 * tv + bias[c];
    out[(size_t)node * 64 + lane] = f2bf(fmaxf(h * sc + sh, 0.0f));
}

// ---------------- parallel pool: wave per 64-node chunk, lane = channel ----------------

__global__ __launch_bounds__(256)
void pool_sum_kernel(const unsigned short* __restrict__ h3, const int* __restrict__ batch,
                     float* __restrict__ sums, int Nn) {
    int wid  = (int)((blockIdx.x * 256 + threadIdx.x) >> 6);
    int lane = threadIdx.x & 63;
    int i0 = wid * 64;
    if (i0 >= Nn) return;
    int i1 = i0 + 64; if (i1 > Nn) i1 = Nn;

    float acc = 0.0f;
    int g = batch[i0];
    for (int i = i0; i < i1; ++i) {
        int gi = batch[i];
        if (gi != g) {
            unsafeAtomicAdd(&sums[g * 64 + lane], acc);
            acc = 0.0f;
            g = gi;
        }
        acc += bf2f(h3[(size_t)i * 64 + lane]);
    }
    unsafeAtomicAdd(&sums[g * 64 + lane], acc);
}

// ---------------- MLP head on pooled sums ----------------

__global__ __launch_bounds__(64)
void mlp_kernel(const float* __restrict__ sums, const int* __restrict__ start,
                const float* __restrict__ Wm1, const float* __restrict__ bm1,
                const float* __restrict__ Wm2, const float* __restrict__ bm2,
                float* __restrict__ out) {
    int g = blockIdx.x;
    int c = threadIdx.x;  // 64
    float cnt = (float)(start[g + 1] - start[g]);
    float pooled = sums[g * 64 + c] / fmaxf(cnt, 1.0f);
    __shared__ float pl[64];
    __shared__ float zl[64];
    pl[c] = pooled;
    __syncthreads();
    float z = bm1[c];
    for (int j = 0; j < 64; ++j) z = fmaf(pl[j], Wm1[j * 64 + c], z);
    z = fmaxf(z, 0.0f);
    zl[c] = z;
    __syncthreads();
    if (c < 10) {
        float o = bm2[c];
        for (int j = 0; j < 64; ++j) o = fmaf(zl[j], Wm2[j * 10 + c], o);
        out[g * 10 + c] = o;
    }
}

// ---------------- launcher ----------------

static inline int cdiv(int a, int b) { return (a + b - 1) / b; }

extern "C" void kernel_launch(void* const* d_in, const int* in_sizes, int n_in,
                              void* d_out, int out_size, void* d_ws, size_t ws_size,
                              hipStream_t stream) {
    const float* x   = (const float*)d_in[0];
    const int* edge  = (const int*)d_in[1];
    const int* batch = (const int*)d_in[2];
    const float* W1  = (const float*)d_in[3];
    const float* b1  = (const float*)d_in[4];
    const float* W2  = (const float*)d_in[5];
    const float* b2  = (const float*)d_in[6];
    const float* W3  = (const float*)d_in[7];
    const float* b3  = (const float*)d_in[8];
    const float* g1  = (const float*)d_in[9];
    const float* be1 = (const float*)d_in[10];
    const float* m1  = (const float*)d_in[11];
    const float* v1  = (const float*)d_in[12];
    const float* g2  = (const float*)d_in[13];
    const float* be2 = (const float*)d_in[14];
    const float* m2  = (const float*)d_in[15];
    const float* v2  = (const float*)d_in[16];
    const float* g3  = (const float*)d_in[17];
    const float* be3 = (const float*)d_in[18];
    const float* m3  = (const float*)d_in[19];
    const float* v3  = (const float*)d_in[20];
    const float* Wm1 = (const float*)d_in[21];
    const float* bm1 = (const float*)d_in[22];
    const float* Wm2 = (const float*)d_in[23];
    const float* bm2 = (const float*)d_in[24];
    float* outp = (float*)d_out;

    const int Nn = in_sizes[0] / 128;
    const int E  = in_sizes[1] / 2;
    const int G  = 128;
    const int* srcv = edge;
    const int* dstv = edge + E;

    // ws layout (bytes):
    // bufA (Nn*128 bf16) | bufB (Nn*128 bf16) | dinv (Nn f32) | cw (E int2)
    // | row_ptr (Nn+1 int) | start (G+1 int) | sums (G*64 f32)
    char* wsb = (char*)d_ws;
    unsigned short* bufA = (unsigned short*)wsb;
    unsigned short* bufB = bufA + (size_t)Nn * 128;
    float* dinv    = (float*)(bufB + (size_t)Nn * 128);
    int2*  cw      = (int2*)(dinv + Nn);
    int*   row_ptr = (int*)(cw + E);
    int*   start   = row_ptr + (Nn + 1);
    float* sums    = (float*)(start + (G + 1));

    // transient ints overlaid on bufA (free until GEMM1 writes it)
    int* cnt  = (int*)bufA;            // Nn
    int* pos  = cnt + Nn;              // Nn
    int* bsum = pos + Nn;              // cdiv(Nn,256)

    const int TB = 256;
    const int nb = cdiv(Nn, 256);

    // ---- CSR build + norms + graph boundaries ----
    hipMemsetAsync(cnt, 0, (size_t)Nn * sizeof(int), stream);
    count_kernel<<<cdiv(E, TB), TB, 0, stream>>>(dstv, cnt, E);
    dinv_kernel<<<cdiv(Nn, TB), TB, 0, stream>>>(cnt, dinv, Nn);
    scan_block_kernel<<<nb, 256, 0, stream>>>(cnt, row_ptr, bsum, Nn);
    scan_sums_kernel<<<1, 512, 0, stream>>>(bsum, nb);
    add_offsets_kernel<<<nb, 256, 0, stream>>>(row_ptr, bsum, pos, Nn, E);
    scatter_kernel<<<256 * 8, 256, 0, stream>>>(srcv, dstv, dinv, pos, cw, E, Nn);
    boundary_kernel<<<cdiv(Nn, TB), TB, 0, stream>>>(batch, start, Nn, G);

    // ---- layer 1: t = x @ W1 (128->128, f32 in, bf16 out); gather -> bufB ----
    gemm_k<128, 128, 32, 8, 8, 128, 128, false><<<cdiv(Nn, 128), 256, 0, stream>>>(x, W1, bufA, Nn);
    gcn_gather128<<<cdiv(Nn, 4), 256, 0, stream>>>(bufA, bufB, row_ptr, cw, dinv,
                                                   b1, g1, be1, m1, v1, Nn);

    // ---- layer 2: t = h1 @ W2 (128->64, bf16 in/out) ----
    gemm_k<256, 64, 32, 8, 8, 128, 64, true><<<cdiv(Nn, 256), 256, 0, stream>>>(bufB, W2, bufA, Nn);
    gcn_gather64<<<cdiv(Nn, 4), 256, 0, stream>>>(bufA, bufB, row_ptr, cw, dinv,
                                                  b2, g2, be2, m2, v2, Nn);

    // ---- layer 3: t = h2 @ W3 (64->64, bf16 in/out) ----
    gemm_k<256, 64, 32, 8, 8, 64, 64, true><<<cdiv(Nn, 256), 256, 0, stream>>>(bufB, W3, bufA, Nn);
    gcn_gather64<<<cdiv(Nn, 4), 256, 0, stream>>>(bufA, bufB, row_ptr, cw, dinv,
                                                  b3, g3, be3, m3, v3, Nn);

    // ---- pool + MLP ----
    hipMemsetAsync(sums, 0, (size_t)G * 64 * sizeof(float), stream);
    pool_sum_kernel<<<cdiv(Nn, 256), 256, 0, stream>>>(bufB, batch, sums, Nn);
    mlp_kernel<<<G, 64, 0, stream>>>(sums, start, Wm1, bm1, Wm2, bm2, outp);
}

// Round 10
// 474.954 us; speedup vs baseline: 12.2929x; 1.0907x over previous
//
#include <hip/hip_runtime.h>
#include <math.h>

#define BN_EPS 1e-5f

using bf16x8 = __attribute__((ext_vector_type(8))) short;
using f32x4  = __attribute__((ext_vector_type(4))) float;

// ---------------- bf16 helpers (RNE) ----------------

__device__ __forceinline__ float bf2f(unsigned short u) {
    union { unsigned int i; float f; } v; v.i = ((unsigned int)u) << 16; return v.f;
}
__device__ __forceinline__ unsigned short f2bf(float f) {
    union { float f; unsigned int i; } v; v.f = f;
    unsigned int lsb = (v.i >> 16) & 1u;
    v.i += 0x7fffu + lsb;
    return (unsigned short)(v.i >> 16);
}
__device__ __forceinline__ unsigned int pack2bf(float a, float b) {
    return (unsigned int)f2bf(a) | ((unsigned int)f2bf(b) << 16);
}

// ---------------- CSR build: count / scan / scatter ----------------

__global__ void count_kernel(const int* __restrict__ dstv, int* __restrict__ cnt, int E) {
    int e = blockIdx.x * blockDim.x + threadIdx.x;
    if (e < E) atomicAdd(&cnt[dstv[e]], 1);
}

__global__ void dinv_kernel(const int* __restrict__ cnt, float* __restrict__ dinv, int n) {
    int i = blockIdx.x * blockDim.x + threadIdx.x;
    if (i < n) dinv[i] = rsqrtf((float)cnt[i] + 1.0f);  // +1 self-loop
}

__global__ void scan_block_kernel(const int* __restrict__ cnt, int* __restrict__ out,
                                  int* __restrict__ bsum, int Nn) {
    __shared__ int s[256];
    int t = threadIdx.x;
    int i = blockIdx.x * 256 + t;
    int v = (i < Nn) ? cnt[i] : 0;
    s[t] = v;
    __syncthreads();
    for (int off = 1; off < 256; off <<= 1) {
        int add = (t >= off) ? s[t - off] : 0;
        __syncthreads();
        s[t] += add;
        __syncthreads();
    }
    if (i < Nn) out[i] = s[t] - v;
    if (t == 255) bsum[blockIdx.x] = s[255];
}

__global__ void scan_sums_kernel(int* __restrict__ bsum, int nb) {
    __shared__ int s[512];
    int t = threadIdx.x;
    int v = (t < nb) ? bsum[t] : 0;
    s[t] = v;
    __syncthreads();
    for (int off = 1; off < 512; off <<= 1) {
        int add = (t >= off) ? s[t - off] : 0;
        __syncthreads();
        s[t] += add;
        __syncthreads();
    }
    if (t < nb) bsum[t] = s[t] - v;
}

__global__ void add_offsets_kernel(int* __restrict__ row_ptr, const int* __restrict__ bsum,
                                   int* __restrict__ pos, int Nn, int E) {
    int i = blockIdx.x * 256 + threadIdx.x;
    if (i < Nn) {
        int v = row_ptr[i] + bsum[blockIdx.x];
        row_ptr[i] = v;
        pos[i] = v;
    }
    if (i == 0) row_ptr[Nn] = E;
}

// dst-partitioned scatter: part = blockIdx&7 -> one XCD per dst-range
__global__ __launch_bounds__(256)
void scatter_kernel(const int* __restrict__ srcv, const int* __restrict__ dstv,
                    const float* __restrict__ dinv,
                    int* __restrict__ pos, int2* __restrict__ cw, int E, int Nn) {
    int part    = blockIdx.x & 7;
    int chunk   = blockIdx.x >> 3;
    int nchunks = gridDim.x >> 3;
    int lo = (int)((long long)part * Nn >> 3);
    int hi = (part == 7) ? Nn : (int)((long long)(part + 1) * Nn >> 3);
    for (int e = chunk * 256 + threadIdx.x; e < E; e += nchunks * 256) {
        int d = dstv[e];
        if (d >= lo && d < hi) {
            int s = srcv[e];
            float w = dinv[s];
            int p = atomicAdd(&pos[d], 1);
            cw[p] = make_int2(s, __float_as_int(w));
        }
    }
}

__global__ void boundary_kernel(const int* __restrict__ batch, int* __restrict__ start,
                                int Nn, int G) {
    int i = blockIdx.x * blockDim.x + threadIdx.x;
    if (i >= Nn) return;
    int b = batch[i];
    if (i == 0) {
        for (int g = 0; g <= b; ++g) start[g] = 0;
    } else {
        int p = batch[i - 1];
        for (int g = p + 1; g <= b; ++g) start[g] = i;
    }
    if (i == Nn - 1) {
        for (int g = b + 1; g <= G; ++g) start[g] = Nn;
    }
}

// ---------------- weight f32 -> bf16 conversion ----------------

__global__ void convw_kernel(const float* __restrict__ W1, const float* __restrict__ W2,
                             const float* __restrict__ W3,
                             unsigned short* __restrict__ w1b, unsigned short* __restrict__ w2b,
                             unsigned short* __restrict__ w3b) {
    int i = blockIdx.x * 256 + threadIdx.x;
    if (i < 128 * 128) w1b[i] = f2bf(W1[i]);
    if (i < 128 * 64)  w2b[i] = f2bf(W2[i]);
    if (i < 64 * 64)   w3b[i] = f2bf(W3[i]);
}

// ---------------- MFMA GEMM: C[M,N](bf16) = A[M,K](f32|bf16) @ Wb[K,N](bf16) ----------------
// 4 waves/block, wave owns 16 rows. Full W in LDS, pre-swizzled to B-frag layout.
// mfma_f32_16x16x32_bf16 layouts: A row=lane&15, k=(lane>>4)*8+j;
// B col=lane&15, k=(lane>>4)*8+j; D col=lane&15, row=(lane>>4)*4+j.

template<int K, int N, bool AF32>
__global__ __launch_bounds__(256)
void gemm_mfma(const void* __restrict__ Ap, const unsigned short* __restrict__ Wb,
               unsigned short* __restrict__ C, int M) {
    constexpr int KF = K / 32;
    constexpr int NF = N / 16;
    __shared__ __align__(16) unsigned short ldsW[KF * NF * 64 * 8];

    // fill swizzled B frags: coalesced global read, scattered LDS write
    for (int c = threadIdx.x; c < K * N / 8; c += 256) {
        int e0 = c * 8;
        int k = e0 / N, n0 = e0 % N;
        uint4 v = *(const uint4*)&Wb[e0];
        unsigned short w[8];
        w[0] = (unsigned short)(v.x & 0xffff); w[1] = (unsigned short)(v.x >> 16);
        w[2] = (unsigned short)(v.y & 0xffff); w[3] = (unsigned short)(v.y >> 16);
        w[4] = (unsigned short)(v.z & 0xffff); w[5] = (unsigned short)(v.z >> 16);
        w[6] = (unsigned short)(v.w & 0xffff); w[7] = (unsigned short)(v.w >> 16);
        int j    = k & 7;
        int lhi  = ((k & 31) >> 3) << 4;
        int fbase = (k >> 5) * NF;
        #pragma unroll
        for (int u = 0; u < 8; ++u) {
            int n = n0 + u;
            int f = fbase + (n >> 4);
            int l = lhi | (n & 15);
            ldsW[(f * 64 + l) * 8 + j] = w[u];
        }
    }
    __syncthreads();

    const int wave = threadIdx.x >> 6;
    const int lane = threadIdx.x & 63;
    const int r0   = blockIdx.x * 64 + wave * 16;

    // A frags
    int arow = r0 + (lane & 15);
    if (arow >= M) arow = M - 1;
    const int kc0 = (lane >> 4) * 8;
    bf16x8 af[KF];
    #pragma unroll
    for (int k = 0; k < KF; ++k) {
        if constexpr (AF32) {
            const float* A = (const float*)Ap;
            const float4* p = (const float4*)&A[(size_t)arow * K + k * 32 + kc0];
            float4 u0 = p[0], u1 = p[1];
            unsigned int q0 = pack2bf(u0.x, u0.y), q1 = pack2bf(u0.z, u0.w);
            unsigned int q2 = pack2bf(u1.x, u1.y), q3 = pack2bf(u1.z, u1.w);
            bf16x8 a;
            a[0] = (short)(q0 & 0xffff); a[1] = (short)(q0 >> 16);
            a[2] = (short)(q1 & 0xffff); a[3] = (short)(q1 >> 16);
            a[4] = (short)(q2 & 0xffff); a[5] = (short)(q2 >> 16);
            a[6] = (short)(q3 & 0xffff); a[7] = (short)(q3 >> 16);
            af[k] = a;
        } else {
            const unsigned short* A = (const unsigned short*)Ap;
            af[k] = *(const bf16x8*)&A[(size_t)arow * K + k * 32 + kc0];
        }
    }

    const int colb = lane & 15;
    const int rsub = (lane >> 4) * 4;
    #pragma unroll
    for (int n = 0; n < NF; ++n) {
        f32x4 acc = {0.f, 0.f, 0.f, 0.f};
        #pragma unroll
        for (int k = 0; k < KF; ++k) {
            bf16x8 bf = *(const bf16x8*)&ldsW[((k * NF + n) * 64 + lane) * 8];
            acc = __builtin_amdgcn_mfma_f32_16x16x32_bf16(af[k], bf, acc, 0, 0, 0);
        }
        int col = n * 16 + colb;
        #pragma unroll
        for (int j = 0; j < 4; ++j) {
            int row = r0 + rsub + j;
            if (row < M) C[(size_t)row * N + col] = f2bf(acc[j]);
        }
    }
}

// ---------------- fused gather + self-loop + bias + BN + ReLU (bf16 in/out) ----------------

__global__ __launch_bounds__(256)
void gcn_gather128(const unsigned short* __restrict__ t, unsigned short* __restrict__ out,
                   const int* __restrict__ row_ptr, const int2* __restrict__ cw,
                   const float* __restrict__ dinv,
                   const float* __restrict__ bias,
                   const float* __restrict__ gam, const float* __restrict__ bet,
                   const float* __restrict__ mu,  const float* __restrict__ var,
                   int Nn) {
    int node = (int)((blockIdx.x * 256 + threadIdx.x) >> 6);
    int lane = threadIdx.x & 63;
    if (node >= Nn) return;

    int b0 = row_ptr[node];
    int b1 = row_ptr[node + 1];
    float di = dinv[node];
    const unsigned int* tu = (const unsigned int*)t;

    float acc0 = 0.0f, acc1 = 0.0f;
    int e = b0;
    for (; e + 8 <= b1; e += 8) {
        int2 c8[8];
        unsigned int f[8];
        #pragma unroll
        for (int u = 0; u < 8; ++u) c8[u] = cw[e + u];
        #pragma unroll
        for (int u = 0; u < 8; ++u) f[u] = tu[(size_t)c8[u].x * 64 + lane];
        #pragma unroll
        for (int u = 0; u < 8; ++u) {
            float w = __int_as_float(c8[u].y);
            acc0 = fmaf(w, bf2f((unsigned short)(f[u] & 0xffff)), acc0);
            acc1 = fmaf(w, bf2f((unsigned short)(f[u] >> 16)),   acc1);
        }
    }
    for (; e < b1; ++e) {
        int2 c = cw[e];
        unsigned int f = tu[(size_t)c.x * 64 + lane];
        float w = __int_as_float(c.y);
        acc0 = fmaf(w, bf2f((unsigned short)(f & 0xffff)), acc0);
        acc1 = fmaf(w, bf2f((unsigned short)(f >> 16)),   acc1);
    }

    float d2 = di * di;
    unsigned int tv = tu[(size_t)node * 64 + lane];
    int c0 = 2 * lane, c1 = 2 * lane + 1;
    float sc0 = gam[c0] * rsqrtf(var[c0] + BN_EPS);
    float sc1 = gam[c1] * rsqrtf(var[c1] + BN_EPS);
    float sh0 = bet[c0] - mu[c0] * sc0;
    float sh1 = bet[c1] - mu[c1] * sc1;
    float h0 = di * acc0 + d2 * bf2f((unsigned short)(tv & 0xffff)) + bias[c0];
    float h1 = di * acc1 + d2 * bf2f((unsigned short)(tv >> 16))   + bias[c1];
    float o0 = fmaxf(h0 * sc0 + sh0, 0.0f);
    float o1 = fmaxf(h1 * sc1 + sh1, 0.0f);
    ((unsigned int*)out)[(size_t)node * 64 + lane] = pack2bf(o0, o1);
}

__global__ __launch_bounds__(256)
void gcn_gather64(const unsigned short* __restrict__ t, unsigned short* __restrict__ out,
                  const int* __restrict__ row_ptr, const int2* __restrict__ cw,
                  const float* __restrict__ dinv,
                  const float* __restrict__ bias,
                  const float* __restrict__ gam, const float* __restrict__ bet,
                  const float* __restrict__ mu,  const float* __restrict__ var,
                  int Nn) {
    int node = (int)((blockIdx.x * 256 + threadIdx.x) >> 6);
    int lane = threadIdx.x & 63;
    if (node >= Nn) return;

    int b0 = row_ptr[node];
    int b1 = row_ptr[node + 1];
    float di = dinv[node];

    float acc = 0.0f;
    int e = b0;
    for (; e + 8 <= b1; e += 8) {
        int2 c8[8];
        unsigned short f[8];
        #pragma unroll
        for (int u = 0; u < 8; ++u) c8[u] = cw[e + u];
        #pragma unroll
        for (int u = 0; u < 8; ++u) f[u] = t[(size_t)c8[u].x * 64 + lane];
        #pragma unroll
        for (int u = 0; u < 8; ++u)
            acc = fmaf(__int_as_float(c8[u].y), bf2f(f[u]), acc);
    }
    for (; e < b1; ++e) {
        int2 c = cw[e];
        acc = fmaf(__int_as_float(c.y), bf2f(t[(size_t)c.x * 64 + lane]), acc);
    }

    float d2 = di * di;
    float tv = bf2f(t[(size_t)node * 64 + lane]);
    int c = lane;
    float sc = gam[c] * rsqrtf(var[c] + BN_EPS);
    float sh = bet[c] - mu[c] * sc;
    float h  = di * acc + d2 * tv + bias[c];
    out[(size_t)node * 64 + lane] = f2bf(fmaxf(h * sc + sh, 0.0f));
}

// ---------------- parallel pool: wave per 64-node chunk, lane = channel ----------------

__global__ __launch_bounds__(256)
void pool_sum_kernel(const unsigned short* __restrict__ h3, const int* __restrict__ batch,
                     float* __restrict__ sums, int Nn) {
    int wid  = (int)((blockIdx.x * 256 + threadIdx.x) >> 6);
    int lane = threadIdx.x & 63;
    int i0 = wid * 64;
    if (i0 >= Nn) return;
    int i1 = i0 + 64; if (i1 > Nn) i1 = Nn;

    float acc = 0.0f;
    int g = batch[i0];
    for (int i = i0; i < i1; ++i) {
        int gi = batch[i];
        if (gi != g) {
            unsafeAtomicAdd(&sums[g * 64 + lane], acc);
            acc = 0.0f;
            g = gi;
        }
        acc += bf2f(h3[(size_t)i * 64 + lane]);
    }
    unsafeAtomicAdd(&sums[g * 64 + lane], acc);
}

// ---------------- MLP head on pooled sums ----------------

__global__ __launch_bounds__(64)
void mlp_kernel(const float* __restrict__ sums, const int* __restrict__ start,
                const float* __restrict__ Wm1, const float* __restrict__ bm1,
                const float* __restrict__ Wm2, const float* __restrict__ bm2,
                float* __restrict__ out) {
    int g = blockIdx.x;
    int c = threadIdx.x;  // 64
    float cnt = (float)(start[g + 1] - start[g]);
    float pooled = sums[g * 64 + c] / fmaxf(cnt, 1.0f);
    __shared__ float pl[64];
    __shared__ float zl[64];
    pl[c] = pooled;
    __syncthreads();
    float z = bm1[c];
    for (int j = 0; j < 64; ++j) z = fmaf(pl[j], Wm1[j * 64 + c], z);
    z = fmaxf(z, 0.0f);
    zl[c] = z;
    __syncthreads();
    if (c < 10) {
        float o = bm2[c];
        for (int j = 0; j < 64; ++j) o = fmaf(zl[j], Wm2[j * 10 + c], o);
        out[g * 10 + c] = o;
    }
}

// ---------------- launcher ----------------

static inline int cdiv(int a, int b) { return (a + b - 1) / b; }

extern "C" void kernel_launch(void* const* d_in, const int* in_sizes, int n_in,
                              void* d_out, int out_size, void* d_ws, size_t ws_size,
                              hipStream_t stream) {
    const float* x   = (const float*)d_in[0];
    const int* edge  = (const int*)d_in[1];
    const int* batch = (const int*)d_in[2];
    const float* W1  = (const float*)d_in[3];
    const float* b1  = (const float*)d_in[4];
    const float* W2  = (const float*)d_in[5];
    const float* b2  = (const float*)d_in[6];
    const float* W3  = (const float*)d_in[7];
    const float* b3  = (const float*)d_in[8];
    const float* g1  = (const float*)d_in[9];
    const float* be1 = (const float*)d_in[10];
    const float* m1  = (const float*)d_in[11];
    const float* v1  = (const float*)d_in[12];
    const float* g2  = (const float*)d_in[13];
    const float* be2 = (const float*)d_in[14];
    const float* m2  = (const float*)d_in[15];
    const float* v2  = (const float*)d_in[16];
    const float* g3  = (const float*)d_in[17];
    const float* be3 = (const float*)d_in[18];
    const float* m3  = (const float*)d_in[19];
    const float* v3  = (const float*)d_in[20];
    const float* Wm1 = (const float*)d_in[21];
    const float* bm1 = (const float*)d_in[22];
    const float* Wm2 = (const float*)d_in[23];
    const float* bm2 = (const float*)d_in[24];
    float* outp = (float*)d_out;

    const int Nn = in_sizes[0] / 128;
    const int E  = in_sizes[1] / 2;
    const int G  = 128;
    const int* srcv = edge;
    const int* dstv = edge + E;

    // ws layout (bytes):
    // bufA (Nn*128 bf16) | bufB (Nn*128 bf16) | dinv (Nn f32) | cw (E int2)
    // | row_ptr (Nn+1 int) | start (G+1 int) | sums (G*64 f32) | w1b/w2b/w3b (bf16)
    char* wsb = (char*)d_ws;
    unsigned short* bufA = (unsigned short*)wsb;
    unsigned short* bufB = bufA + (size_t)Nn * 128;
    float* dinv    = (float*)(bufB + (size_t)Nn * 128);
    int2*  cw      = (int2*)(dinv + Nn);
    int*   row_ptr = (int*)(cw + E);
    int*   start   = row_ptr + (Nn + 1);
    float* sums    = (float*)(start + (G + 1));
    unsigned short* w1b = (unsigned short*)(sums + G * 64);
    unsigned short* w2b = w1b + 128 * 128;
    unsigned short* w3b = w2b + 128 * 64;

    // transient ints overlaid on bufA (free until GEMM1 writes it)
    int* cnt  = (int*)bufA;            // Nn
    int* pos  = cnt + Nn;              // Nn
    int* bsum = pos + Nn;              // cdiv(Nn,256)

    const int TB = 256;
    const int nb = cdiv(Nn, 256);

    // ---- CSR build + norms + weight conversion + graph boundaries ----
    hipMemsetAsync(cnt, 0, (size_t)Nn * sizeof(int), stream);
    count_kernel<<<cdiv(E, TB), TB, 0, stream>>>(dstv, cnt, E);
    dinv_kernel<<<cdiv(Nn, TB), TB, 0, stream>>>(cnt, dinv, Nn);
    scan_block_kernel<<<nb, 256, 0, stream>>>(cnt, row_ptr, bsum, Nn);
    scan_sums_kernel<<<1, 512, 0, stream>>>(bsum, nb);
    add_offsets_kernel<<<nb, 256, 0, stream>>>(row_ptr, bsum, pos, Nn, E);
    scatter_kernel<<<256 * 8, 256, 0, stream>>>(srcv, dstv, dinv, pos, cw, E, Nn);
    convw_kernel<<<64, 256, 0, stream>>>(W1, W2, W3, w1b, w2b, w3b);
    boundary_kernel<<<cdiv(Nn, TB), TB, 0, stream>>>(batch, start, Nn, G);

    // ---- layer 1: t = x @ W1 (128->128, f32 A -> bf16); gather -> bufB ----
    gemm_mfma<128, 128, true><<<cdiv(Nn, 64), 256, 0, stream>>>(x, w1b, bufA, Nn);
    gcn_gather128<<<cdiv(Nn, 4), 256, 0, stream>>>(bufA, bufB, row_ptr, cw, dinv,
                                                   b1, g1, be1, m1, v1, Nn);

    // ---- layer 2: t = h1 @ W2 (128->64) ----
    gemm_mfma<128, 64, false><<<cdiv(Nn, 64), 256, 0, stream>>>(bufB, w2b, bufA, Nn);
    gcn_gather64<<<cdiv(Nn, 4), 256, 0, stream>>>(bufA, bufB, row_ptr, cw, dinv,
                                                  b2, g2, be2, m2, v2, Nn);

    // ---- layer 3: t = h2 @ W3 (64->64) ----
    gemm_mfma<64, 64, false><<<cdiv(Nn, 64), 256, 0, stream>>>(bufB, w3b, bufA, Nn);
    gcn_gather64<<<cdiv(Nn, 4), 256, 0, stream>>>(bufA, bufB, row_ptr, cw, dinv,
                                                  b3, g3, be3, m3, v3, Nn);

    // ---- pool + MLP ----
    hipMemsetAsync(sums, 0, (size_t)G * 64 * sizeof(float), stream);
    pool_sum_kernel<<<cdiv(Nn, 256), 256, 0, stream>>>(bufB, batch, sums, Nn);
    mlp_kernel<<<G, 64, 0, stream>>>(sums, start, Wm1, bm1, Wm2, bm2, outp);
}

// Round 11
// 453.510 us; speedup vs baseline: 12.8742x; 1.0473x over previous
//
#include <hip/hip_runtime.h>
#include <math.h>

#define BN_EPS 1e-5f

using bf16x8 = __attribute__((ext_vector_type(8))) short;
using f32x4  = __attribute__((ext_vector_type(4))) float;

// ---------------- bf16 helpers (RNE) ----------------

__device__ __forceinline__ float bf2f(unsigned short u) {
    union { unsigned int i; float f; } v; v.i = ((unsigned int)u) << 16; return v.f;
}
__device__ __forceinline__ unsigned short f2bf(float f) {
    union { float f; unsigned int i; } v; v.f = f;
    unsigned int lsb = (v.i >> 16) & 1u;
    v.i += 0x7fffu + lsb;
    return (unsigned short)(v.i >> 16);
}
__device__ __forceinline__ unsigned int pack2bf(float a, float b) {
    return (unsigned int)f2bf(a) | ((unsigned int)f2bf(b) << 16);
}

// ---------------- CSR build ----------------

__global__ void count_kernel(const int* __restrict__ dstv, int* __restrict__ cnt, int E) {
    int e = blockIdx.x * blockDim.x + threadIdx.x;
    if (e < E) atomicAdd(&cnt[dstv[e]], 1);
}

// block scan + dinv (fused)
__global__ void scan_block_kernel(const int* __restrict__ cnt, int* __restrict__ out,
                                  int* __restrict__ bsum, float* __restrict__ dinv, int Nn) {
    __shared__ int s[256];
    int t = threadIdx.x;
    int i = blockIdx.x * 256 + t;
    int v = (i < Nn) ? cnt[i] : 0;
    if (i < Nn) dinv[i] = rsqrtf((float)v + 1.0f);  // +1 self-loop
    s[t] = v;
    __syncthreads();
    for (int off = 1; off < 256; off <<= 1) {
        int add = (t >= off) ? s[t - off] : 0;
        __syncthreads();
        s[t] += add;
        __syncthreads();
    }
    if (i < Nn) out[i] = s[t] - v;
    if (t == 255) bsum[blockIdx.x] = s[255];
}

__global__ void scan_sums_kernel(int* __restrict__ bsum, int nb) {
    __shared__ int s[512];
    int t = threadIdx.x;
    int v = (t < nb) ? bsum[t] : 0;
    s[t] = v;
    __syncthreads();
    for (int off = 1; off < 512; off <<= 1) {
        int add = (t >= off) ? s[t - off] : 0;
        __syncthreads();
        s[t] += add;
        __syncthreads();
    }
    if (t < nb) bsum[t] = s[t] - v;
}

// add block offsets, init pos, AND graph boundaries (fused)
__global__ void add_offsets_kernel(int* __restrict__ row_ptr, const int* __restrict__ bsum,
                                   int* __restrict__ pos,
                                   const int* __restrict__ batch, int* __restrict__ start,
                                   int Nn, int E, int G) {
    int i = blockIdx.x * 256 + threadIdx.x;
    if (i < Nn) {
        int v = row_ptr[i] + bsum[blockIdx.x];
        row_ptr[i] = v;
        pos[i] = v;
        int b = batch[i];
        if (i == 0) {
            for (int g = 0; g <= b; ++g) start[g] = 0;
        } else {
            int p = batch[i - 1];
            for (int g = p + 1; g <= b; ++g) start[g] = i;
        }
        if (i == Nn - 1) {
            for (int g = b + 1; g <= G; ++g) start[g] = Nn;
        }
    }
    if (i == 0) row_ptr[Nn] = E;
}

// dst-partitioned scatter: part = blockIdx&7 -> one XCD per dst-range
__global__ __launch_bounds__(256)
void scatter_kernel(const int* __restrict__ srcv, const int* __restrict__ dstv,
                    const float* __restrict__ dinv,
                    int* __restrict__ pos, int2* __restrict__ cw, int E, int Nn) {
    int part    = blockIdx.x & 7;
    int chunk   = blockIdx.x >> 3;
    int nchunks = gridDim.x >> 3;
    int lo = (int)((long long)part * Nn >> 3);
    int hi = (part == 7) ? Nn : (int)((long long)(part + 1) * Nn >> 3);
    for (int e = chunk * 256 + threadIdx.x; e < E; e += nchunks * 256) {
        int d = dstv[e];
        if (d >= lo && d < hi) {
            int s = srcv[e];
            float w = dinv[s];
            int p = atomicAdd(&pos[d], 1);
            cw[p] = make_int2(s, __float_as_int(w));
        }
    }
}

// ---------------- weight f32 -> bf16 conversion ----------------

__global__ void convw_kernel(const float* __restrict__ W1, const float* __restrict__ W2,
                             const float* __restrict__ W3,
                             unsigned short* __restrict__ w1b, unsigned short* __restrict__ w2b,
                             unsigned short* __restrict__ w3b) {
    int i = blockIdx.x * 256 + threadIdx.x;
    if (i < 128 * 128) w1b[i] = f2bf(W1[i]);
    if (i < 128 * 64)  w2b[i] = f2bf(W2[i]);
    if (i < 64 * 64)   w3b[i] = f2bf(W3[i]);
}

// ---------------- MFMA GEMM: C[M,N](bf16) = A[M,K](f32|bf16) @ Wb[K,N](bf16) ----------------

template<int K, int N, bool AF32>
__global__ __launch_bounds__(256)
void gemm_mfma(const void* __restrict__ Ap, const unsigned short* __restrict__ Wb,
               unsigned short* __restrict__ C, int M) {
    constexpr int KF = K / 32;
    constexpr int NF = N / 16;
    __shared__ __align__(16) unsigned short ldsW[KF * NF * 64 * 8];

    for (int c = threadIdx.x; c < K * N / 8; c += 256) {
        int e0 = c * 8;
        int k = e0 / N, n0 = e0 % N;
        uint4 v = *(const uint4*)&Wb[e0];
        unsigned short w[8];
        w[0] = (unsigned short)(v.x & 0xffff); w[1] = (unsigned short)(v.x >> 16);
        w[2] = (unsigned short)(v.y & 0xffff); w[3] = (unsigned short)(v.y >> 16);
        w[4] = (unsigned short)(v.z & 0xffff); w[5] = (unsigned short)(v.z >> 16);
        w[6] = (unsigned short)(v.w & 0xffff); w[7] = (unsigned short)(v.w >> 16);
        int j    = k & 7;
        int lhi  = ((k & 31) >> 3) << 4;
        int fbase = (k >> 5) * NF;
        #pragma unroll
        for (int u = 0; u < 8; ++u) {
            int n = n0 + u;
            int f = fbase + (n >> 4);
            int l = lhi | (n & 15);
            ldsW[(f * 64 + l) * 8 + j] = w[u];
        }
    }
    __syncthreads();

    const int wave = threadIdx.x >> 6;
    const int lane = threadIdx.x & 63;
    const int r0   = blockIdx.x * 64 + wave * 16;

    int arow = r0 + (lane & 15);
    if (arow >= M) arow = M - 1;
    const int kc0 = (lane >> 4) * 8;
    bf16x8 af[KF];
    #pragma unroll
    for (int k = 0; k < KF; ++k) {
        if constexpr (AF32) {
            const float* A = (const float*)Ap;
            const float4* p = (const float4*)&A[(size_t)arow * K + k * 32 + kc0];
            float4 u0 = p[0], u1 = p[1];
            unsigned int q0 = pack2bf(u0.x, u0.y), q1 = pack2bf(u0.z, u0.w);
            unsigned int q2 = pack2bf(u1.x, u1.y), q3 = pack2bf(u1.z, u1.w);
            bf16x8 a;
            a[0] = (short)(q0 & 0xffff); a[1] = (short)(q0 >> 16);
            a[2] = (short)(q1 & 0xffff); a[3] = (short)(q1 >> 16);
            a[4] = (short)(q2 & 0xffff); a[5] = (short)(q2 >> 16);
            a[6] = (short)(q3 & 0xffff); a[7] = (short)(q3 >> 16);
            af[k] = a;
        } else {
            const unsigned short* A = (const unsigned short*)Ap;
            af[k] = *(const bf16x8*)&A[(size_t)arow * K + k * 32 + kc0];
        }
    }

    const int colb = lane & 15;
    const int rsub = (lane >> 4) * 4;
    #pragma unroll
    for (int n = 0; n < NF; ++n) {
        f32x4 acc = {0.f, 0.f, 0.f, 0.f};
        #pragma unroll
        for (int k = 0; k < KF; ++k) {
            bf16x8 bf = *(const bf16x8*)&ldsW[((k * NF + n) * 64 + lane) * 8];
            acc = __builtin_amdgcn_mfma_f32_16x16x32_bf16(af[k], bf, acc, 0, 0, 0);
        }
        int col = n * 16 + colb;
        #pragma unroll
        for (int j = 0; j < 4; ++j) {
            int row = r0 + rsub + j;
            if (row < M) C[(size_t)row * N + col] = f2bf(acc[j]);
        }
    }
}

// ---------------- fused gather + self-loop + bias + BN + ReLU (bf16 in/out) ----------------
// 16x edge unroll: 16 feature loads in flight per wave.

__global__ __launch_bounds__(256)
void gcn_gather128(const unsigned short* __restrict__ t, unsigned short* __restrict__ out,
                   const int* __restrict__ row_ptr, const int2* __restrict__ cw,
                   const float* __restrict__ dinv,
                   const float* __restrict__ bias,
                   const float* __restrict__ gam, const float* __restrict__ bet,
                   const float* __restrict__ mu,  const float* __restrict__ var,
                   int Nn) {
    int node = (int)((blockIdx.x * 256 + threadIdx.x) >> 6);
    int lane = threadIdx.x & 63;
    if (node >= Nn) return;

    int b0 = row_ptr[node];
    int b1 = row_ptr[node + 1];
    float di = dinv[node];
    const unsigned int* tu = (const unsigned int*)t;

    float acc0 = 0.0f, acc1 = 0.0f;
    int e = b0;
    for (; e + 16 <= b1; e += 16) {
        int2 c16[16];
        unsigned int f[16];
        #pragma unroll
        for (int u = 0; u < 16; ++u) c16[u] = cw[e + u];
        #pragma unroll
        for (int u = 0; u < 16; ++u) f[u] = tu[(size_t)c16[u].x * 64 + lane];
        #pragma unroll
        for (int u = 0; u < 16; ++u) {
            float w = __int_as_float(c16[u].y);
            acc0 = fmaf(w, bf2f((unsigned short)(f[u] & 0xffff)), acc0);
            acc1 = fmaf(w, bf2f((unsigned short)(f[u] >> 16)),   acc1);
        }
    }
    for (; e + 4 <= b1; e += 4) {
        int2 c4[4];
        unsigned int f[4];
        #pragma unroll
        for (int u = 0; u < 4; ++u) c4[u] = cw[e + u];
        #pragma unroll
        for (int u = 0; u < 4; ++u) f[u] = tu[(size_t)c4[u].x * 64 + lane];
        #pragma unroll
        for (int u = 0; u < 4; ++u) {
            float w = __int_as_float(c4[u].y);
            acc0 = fmaf(w, bf2f((unsigned short)(f[u] & 0xffff)), acc0);
            acc1 = fmaf(w, bf2f((unsigned short)(f[u] >> 16)),   acc1);
        }
    }
    for (; e < b1; ++e) {
        int2 c = cw[e];
        unsigned int f = tu[(size_t)c.x * 64 + lane];
        float w = __int_as_float(c.y);
        acc0 = fmaf(w, bf2f((unsigned short)(f & 0xffff)), acc0);
        acc1 = fmaf(w, bf2f((unsigned short)(f >> 16)),   acc1);
    }

    float d2 = di * di;
    unsigned int tv = tu[(size_t)node * 64 + lane];
    int c0 = 2 * lane, c1 = 2 * lane + 1;
    float sc0 = gam[c0] * rsqrtf(var[c0] + BN_EPS);
    float sc1 = gam[c1] * rsqrtf(var[c1] + BN_EPS);
    float sh0 = bet[c0] - mu[c0] * sc0;
    float sh1 = bet[c1] - mu[c1] * sc1;
    float h0 = di * acc0 + d2 * bf2f((unsigned short)(tv & 0xffff)) + bias[c0];
    float h1 = di * acc1 + d2 * bf2f((unsigned short)(tv >> 16))   + bias[c1];
    float o0 = fmaxf(h0 * sc0 + sh0, 0.0f);
    float o1 = fmaxf(h1 * sc1 + sh1, 0.0f);
    ((unsigned int*)out)[(size_t)node * 64 + lane] = pack2bf(o0, o1);
}

__global__ __launch_bounds__(256)
void gcn_gather64(const unsigned short* __restrict__ t, unsigned short* __restrict__ out,
                  const int* __restrict__ row_ptr, const int2* __restrict__ cw,
                  const float* __restrict__ dinv,
                  const float* __restrict__ bias,
                  const float* __restrict__ gam, const float* __restrict__ bet,
                  const float* __restrict__ mu,  const float* __restrict__ var,
                  int Nn) {
    int node = (int)((blockIdx.x * 256 + threadIdx.x) >> 6);
    int lane = threadIdx.x & 63;
    if (node >= Nn) return;

    int b0 = row_ptr[node];
    int b1 = row_ptr[node + 1];
    float di = dinv[node];

    float acc = 0.0f;
    int e = b0;
    for (; e + 16 <= b1; e += 16) {
        int2 c16[16];
        unsigned short f[16];
        #pragma unroll
        for (int u = 0; u < 16; ++u) c16[u] = cw[e + u];
        #pragma unroll
        for (int u = 0; u < 16; ++u) f[u] = t[(size_t)c16[u].x * 64 + lane];
        #pragma unroll
        for (int u = 0; u < 16; ++u)
            acc = fmaf(__int_as_float(c16[u].y), bf2f(f[u]), acc);
    }
    for (; e + 4 <= b1; e += 4) {
        int2 c4[4];
        unsigned short f[4];
        #pragma unroll
        for (int u = 0; u < 4; ++u) c4[u] = cw[e + u];
        #pragma unroll
        for (int u = 0; u < 4; ++u) f[u] = t[(size_t)c4[u].x * 64 + lane];
        #pragma unroll
        for (int u = 0; u < 4; ++u)
            acc = fmaf(__int_as_float(c4[u].y), bf2f(f[u]), acc);
    }
    for (; e < b1; ++e) {
        int2 c = cw[e];
        acc = fmaf(__int_as_float(c.y), bf2f(t[(size_t)c.x * 64 + lane]), acc);
    }

    float d2 = di * di;
    float tv = bf2f(t[(size_t)node * 64 + lane]);
    int c = lane;
    float sc = gam[c] * rsqrtf(var[c] + BN_EPS);
    float sh = bet[c] - mu[c] * sc;
    float h  = di * acc + d2 * tv + bias[c];
    out[(size_t)node * 64 + lane] = f2bf(fmaxf(h * sc + sh, 0.0f));
}

// ---------------- parallel pool: wave per 64-node chunk, lane = channel ----------------

__global__ __launch_bounds__(256)
void pool_sum_kernel(const unsigned short* __restrict__ h3, const int* __restrict__ batch,
                     float* __restrict__ sums, int Nn) {
    int wid  = (int)((blockIdx.x * 256 + threadIdx.x) >> 6);
    int lane = threadIdx.x & 63;
    int i0 = wid * 64;
    if (i0 >= Nn) return;
    int i1 = i0 + 64; if (i1 > Nn) i1 = Nn;

    float acc = 0.0f;
    int g = batch[i0];
    for (int i = i0; i < i1; ++i) {
        int gi = batch[i];
        if (gi != g) {
            unsafeAtomicAdd(&sums[g * 64 + lane], acc);
            acc = 0.0f;
            g = gi;
        }
        acc += bf2f(h3[(size_t)i * 64 + lane]);
    }
    unsafeAtomicAdd(&sums[g * 64 + lane], acc);
}

// ---------------- MLP head on pooled sums ----------------

__global__ __launch_bounds__(64)
void mlp_kernel(const float* __restrict__ sums, const int* __restrict__ start,
                const float* __restrict__ Wm1, const float* __restrict__ bm1,
                const float* __restrict__ Wm2, const float* __restrict__ bm2,
                float* __restrict__ out) {
    int g = blockIdx.x;
    int c = threadIdx.x;  // 64
    float cnt = (float)(start[g + 1] - start[g]);
    float pooled = sums[g * 64 + c] / fmaxf(cnt, 1.0f);
    __shared__ float pl[64];
    __shared__ float zl[64];
    pl[c] = pooled;
    __syncthreads();
    float z = bm1[c];
    for (int j = 0; j < 64; ++j) z = fmaf(pl[j], Wm1[j * 64 + c], z);
    z = fmaxf(z, 0.0f);
    zl[c] = z;
    __syncthreads();
    if (c < 10) {
        float o = bm2[c];
        for (int j = 0; j < 64; ++j) o = fmaf(zl[j], Wm2[j * 10 + c], o);
        out[g * 10 + c] = o;
    }
}

// ---------------- launcher ----------------

static inline int cdiv(int a, int b) { return (a + b - 1) / b; }

extern "C" void kernel_launch(void* const* d_in, const int* in_sizes, int n_in,
                              void* d_out, int out_size, void* d_ws, size_t ws_size,
                              hipStream_t stream) {
    const float* x   = (const float*)d_in[0];
    const int* edge  = (const int*)d_in[1];
    const int* batch = (const int*)d_in[2];
    const float* W1  = (const float*)d_in[3];
    const float* b1  = (const float*)d_in[4];
    const float* W2  = (const float*)d_in[5];
    const float* b2  = (const float*)d_in[6];
    const float* W3  = (const float*)d_in[7];
    const float* b3  = (const float*)d_in[8];
    const float* g1  = (const float*)d_in[9];
    const float* be1 = (const float*)d_in[10];
    const float* m1  = (const float*)d_in[11];
    const float* v1  = (const float*)d_in[12];
    const float* g2  = (const float*)d_in[13];
    const float* be2 = (const float*)d_in[14];
    const float* m2  = (const float*)d_in[15];
    const float* v2  = (const float*)d_in[16];
    const float* g3  = (const float*)d_in[17];
    const float* be3 = (const float*)d_in[18];
    const float* m3  = (const float*)d_in[19];
    const float* v3  = (const float*)d_in[20];
    const float* Wm1 = (const float*)d_in[21];
    const float* bm1 = (const float*)d_in[22];
    const float* Wm2 = (const float*)d_in[23];
    const float* bm2 = (const float*)d_in[24];
    float* outp = (float*)d_out;

    const int Nn = in_sizes[0] / 128;
    const int E  = in_sizes[1] / 2;
    const int G  = 128;
    const int* srcv = edge;
    const int* dstv = edge + E;

    // ws layout (bytes):
    // bufA (Nn*128 bf16) | bufB (Nn*128 bf16) | dinv (Nn f32) | cw (E int2)
    // | row_ptr (Nn+1 int) | start (G+1 int) | sums (G*64 f32) | w1b/w2b/w3b (bf16)
    char* wsb = (char*)d_ws;
    unsigned short* bufA = (unsigned short*)wsb;
    unsigned short* bufB = bufA + (size_t)Nn * 128;
    float* dinv    = (float*)(bufB + (size_t)Nn * 128);
    int2*  cw      = (int2*)(dinv + Nn);
    int*   row_ptr = (int*)(cw + E);
    int*   start   = row_ptr + (Nn + 1);
    float* sums    = (float*)(start + (G + 1));
    unsigned short* w1b = (unsigned short*)(sums + G * 64);
    unsigned short* w2b = w1b + 128 * 128;
    unsigned short* w3b = w2b + 128 * 64;

    // transient ints overlaid on bufA (free until GEMM1 writes it)
    int* cnt  = (int*)bufA;            // Nn
    int* pos  = cnt + Nn;              // Nn
    int* bsum = pos + Nn;              // cdiv(Nn,256)

    const int TB = 256;
    const int nb = cdiv(Nn, 256);

    // ---- CSR build + norms + weight conversion + graph boundaries ----
    hipMemsetAsync(cnt, 0, (size_t)Nn * sizeof(int), stream);
    count_kernel<<<cdiv(E, TB), TB, 0, stream>>>(dstv, cnt, E);
    scan_block_kernel<<<nb, 256, 0, stream>>>(cnt, row_ptr, bsum, dinv, Nn);
    scan_sums_kernel<<<1, 512, 0, stream>>>(bsum, nb);
    add_offsets_kernel<<<nb, 256, 0, stream>>>(row_ptr, bsum, pos, batch, start, Nn, E, G);
    scatter_kernel<<<256 * 8, 256, 0, stream>>>(srcv, dstv, dinv, pos, cw, E, Nn);
    convw_kernel<<<64, 256, 0, stream>>>(W1, W2, W3, w1b, w2b, w3b);

    // ---- layer 1: t = x @ W1 (128->128, f32 A -> bf16); gather -> bufB ----
    gemm_mfma<128, 128, true><<<cdiv(Nn, 64), 256, 0, stream>>>(x, w1b, bufA, Nn);
    gcn_gather128<<<cdiv(Nn, 4), 256, 0, stream>>>(bufA, bufB, row_ptr, cw, dinv,
                                                   b1, g1, be1, m1, v1, Nn);

    // ---- layer 2: t = h1 @ W2 (128->64) ----
    gemm_mfma<128, 64, false><<<cdiv(Nn, 64), 256, 0, stream>>>(bufB, w2b, bufA, Nn);
    gcn_gather64<<<cdiv(Nn, 4), 256, 0, stream>>>(bufA, bufB, row_ptr, cw, dinv,
                                                  b2, g2, be2, m2, v2, Nn);

    // ---- layer 3: t = h2 @ W3 (64->64) ----
    gemm_mfma<64, 64, false><<<cdiv(Nn, 64), 256, 0, stream>>>(bufB, w3b, bufA, Nn);
    gcn_gather64<<<cdiv(Nn, 4), 256, 0, stream>>>(bufA, bufB, row_ptr, cw, dinv,
                                                  b3, g3, be3, m3, v3, Nn);

    // ---- pool + MLP ----
    hipMemsetAsync(sums, 0, (size_t)G * 64 * sizeof(float), stream);
    pool_sum_kernel<<<cdiv(Nn, 256), 256, 0, stream>>>(bufB, batch, sums, Nn);
    mlp_kernel<<<G, 64, 0, stream>>>(sums, start, Wm1, bm1, Wm2, bm2, outp);
}